// Round 4
// baseline (1075.115 us; speedup 1.0000x reference)
//
#include <hip/hip_runtime.h>
#include <math.h>

#define NN 20000
#define NE 200000

typedef __attribute__((ext_vector_type(8))) short bf16x8;
typedef __attribute__((ext_vector_type(8))) unsigned short u16x8;
typedef __attribute__((ext_vector_type(4))) float f32x4;

__device__ __forceinline__ unsigned short f2bf(float x) {
  union { float f; unsigned u; } c; c.f = x;
  unsigned r = c.u + 0x7FFF + ((c.u >> 16) & 1);
  return (unsigned short)(r >> 16);
}
__device__ __forceinline__ float bf2f(unsigned short u) {
  union { unsigned u; float f; } c; c.u = ((unsigned)u) << 16;
  return c.f;
}

// ---------------------------------------------------------------------------
// Encoder v2: ONE THREAD PER ROW. out = relu(LN(in @ W + b)).
// ---------------------------------------------------------------------------
template <int D>
__global__ __launch_bounds__(256) void encode_row_kernel(
    const float* __restrict__ in,
    const float* __restrict__ W, const float* __restrict__ b,
    const float* __restrict__ g, const float* __restrict__ beta,
    float* __restrict__ out, unsigned short* __restrict__ outb, int R) {
  int row = blockIdx.x * 256 + threadIdx.x;
  if (row >= R) return;
  float vin[D];
#pragma unroll
  for (int k = 0; k < D; k++) vin[k] = in[(size_t)row * D + k];
  float y[96];
  float s = 0.f, s2 = 0.f;
#pragma unroll
  for (int j = 0; j < 96; j++) {
    float v = b[j];
#pragma unroll
    for (int k = 0; k < D; k++) v += vin[k] * W[k * 96 + j];
    y[j] = v;
    s += v;
    s2 += v * v;
  }
  float mu = s * (1.f / 96.f);
  float var = s2 * (1.f / 96.f) - mu * mu;
  float rs = rsqrtf(var + 1e-5f);
#pragma unroll
  for (int c = 0; c < 12; c++) {
    u16x8 pk;
    float yo[8];
#pragma unroll
    for (int j = 0; j < 8; j++) {
      int jj = c * 8 + j;
      float v = (y[jj] - mu) * rs * g[jj] + beta[jj];
      v = fmaxf(v, 0.f);
      yo[j] = v;
      pk[j] = f2bf(v);
    }
    *(u16x8*)&outb[(size_t)row * 96 + c * 8] = pk;
    if (out) {
      f32x4 o0 = {yo[0], yo[1], yo[2], yo[3]};
      f32x4 o1 = {yo[4], yo[5], yo[6], yo[7]};
      *(f32x4*)&out[(size_t)row * 96 + c * 8] = o0;
      *(f32x4*)&out[(size_t)row * 96 + c * 8 + 4] = o1;
    }
  }
}

// ---------------------------------------------------------------------------
// Weight prep
// ---------------------------------------------------------------------------
__global__ void convW_kernel(const float* __restrict__ We,
                             unsigned short* __restrict__ WeTb,
                             const float* __restrict__ Wl,
                             unsigned short* __restrict__ WlTb,
                             const float* __restrict__ Wr,
                             unsigned short* __restrict__ WrTb,
                             const float* __restrict__ p1w,
                             unsigned short* __restrict__ p1wT,
                             const float* __restrict__ p2w,
                             unsigned short* __restrict__ p2wT) {
  int idx = blockIdx.x * 256 + threadIdx.x;
  if (idx < 3 * 576 * 96) {
    int l = idx / (576 * 96);
    int rem = idx % (576 * 96);
    int n = rem / 96, k = rem % 96;
    size_t sidx = (size_t)l * 96 * 576 + (size_t)k * 576 + n;
    WeTb[idx] = f2bf(We[sidx]);
    WlTb[idx] = f2bf(Wl[sidx]);
    WrTb[idx] = f2bf(Wr[sidx]);
  }
  if (idx < 128 * 288) {
    int n = idx / 288, k = idx % 288;
    p1wT[idx] = f2bf(p1w[(size_t)k * 128 + n]);
  }
  if (idx < 64 * 128) {
    int n = idx / 128, k = idx % 128;
    p2wT[idx] = f2bf(p2w[(size_t)k * 64 + n]);
  }
}

// ---------------------------------------------------------------------------
// CSR build by dst
// ---------------------------------------------------------------------------
__global__ void hist_kernel(const int* __restrict__ dst, int* __restrict__ deg) {
  int e = blockIdx.x * blockDim.x + threadIdx.x;
  if (e < NE) atomicAdd(&deg[dst[e]], 1);
}

// fast scan: 20 nodes/thread serial prefix + wave shfl scan + 16-wave scan
__global__ __launch_bounds__(1024) void scan_kernel(
    const int* __restrict__ deg, int* __restrict__ rowptr, int* __restrict__ cursor) {
  __shared__ int wsum[16];
  int t = threadIdx.x;
  int base = t * 20;
  int loc[20];
  int s = 0;
#pragma unroll
  for (int j = 0; j < 20; j++) {
    int idx = base + j;
    int v = (idx < NN) ? deg[idx] : 0;
    loc[j] = s;
    s += v;
  }
  int lane = t & 63, wv = t >> 6;
  int inc = s;
#pragma unroll
  for (int off = 1; off < 64; off <<= 1) {
    int up = __shfl_up(inc, off);
    if (lane >= off) inc += up;
  }
  if (lane == 63) wsum[wv] = inc;
  __syncthreads();
  if (wv == 0) {
    int wval = (lane < 16) ? wsum[lane] : 0;
#pragma unroll
    for (int off = 1; off < 16; off <<= 1) {
      int up = __shfl_up(wval, off);
      if (lane >= off) wval += up;
    }
    if (lane < 16) wsum[lane] = wval;
  }
  __syncthreads();
  int wbase = (wv > 0) ? wsum[wv - 1] : 0;
  int excl = wbase + inc - s;
#pragma unroll
  for (int j = 0; j < 20; j++) {
    int idx = base + j;
    if (idx < NN) { rowptr[idx] = excl + loc[j]; cursor[idx] = excl + loc[j]; }
  }
  if (t == 0) rowptr[NN] = NE;
}

__global__ void scatter_kernel(const int* __restrict__ src,
                               const int* __restrict__ dst,
                               int* __restrict__ cursor, int* __restrict__ eidx,
                               int* __restrict__ srcp, int* __restrict__ dstp) {
  int e = blockIdx.x * blockDim.x + threadIdx.x;
  if (e < NE) {
    int d = dst[e];
    int p = atomicAdd(&cursor[d], 1);
    eidx[p] = e;
    srcp[p] = src[e];
    dstp[p] = d;
  }
}

// ---------------------------------------------------------------------------
// xlxr via MFMA (verified R8)
// ---------------------------------------------------------------------------
__global__ __launch_bounds__(256) void xlxr_mfma_kernel(
    const unsigned short* __restrict__ Xb,    // [NN][96]
    const unsigned short* __restrict__ WlTb,  // [576][96]
    const float* __restrict__ bl,
    const unsigned short* __restrict__ WrTb,  // [576][96]
    const float* __restrict__ br,
    unsigned short* __restrict__ xlb, unsigned short* __restrict__ xrb) {
  int t = threadIdx.x;
  int wave = t >> 6, lane = t & 63;
  int l15 = lane & 15, quad = lane >> 4;
  int node = blockIdx.x * 64 + wave * 16 + l15;
  int nclamp = (node < NN) ? node : (NN - 1);
  bool valid = node < NN;
  const unsigned short* brow = &Xb[(size_t)nclamp * 96 + quad * 8];
  bf16x8 b0 = *(const bf16x8*)&brow[0];
  bf16x8 b1 = *(const bf16x8*)&brow[32];
  bf16x8 b2 = *(const bf16x8*)&brow[64];
#pragma unroll
  for (int mt = 0; mt < 36; mt++) {
    int wc = mt * 16 + l15;
    const unsigned short* aL = &WlTb[(size_t)wc * 96 + quad * 8];
    f32x4 accL = {0.f, 0.f, 0.f, 0.f};
    accL = __builtin_amdgcn_mfma_f32_16x16x32_bf16(*(const bf16x8*)&aL[0], b0, accL, 0, 0, 0);
    accL = __builtin_amdgcn_mfma_f32_16x16x32_bf16(*(const bf16x8*)&aL[32], b1, accL, 0, 0, 0);
    accL = __builtin_amdgcn_mfma_f32_16x16x32_bf16(*(const bf16x8*)&aL[64], b2, accL, 0, 0, 0);
    const unsigned short* aR = &WrTb[(size_t)wc * 96 + quad * 8];
    f32x4 accR = {0.f, 0.f, 0.f, 0.f};
    accR = __builtin_amdgcn_mfma_f32_16x16x32_bf16(*(const bf16x8*)&aR[0], b0, accR, 0, 0, 0);
    accR = __builtin_amdgcn_mfma_f32_16x16x32_bf16(*(const bf16x8*)&aR[32], b1, accR, 0, 0, 0);
    accR = __builtin_amdgcn_mfma_f32_16x16x32_bf16(*(const bf16x8*)&aR[64], b2, accR, 0, 0, 0);
    if (valid) {
      int c0 = mt * 16 + quad * 4;
      float4 bbL = *(const float4*)&bl[c0];
      float4 bbR = *(const float4*)&br[c0];
      ushort4 pL, pR;
      pL.x = f2bf(accL[0] + bbL.x); pL.y = f2bf(accL[1] + bbL.y);
      pL.z = f2bf(accL[2] + bbL.z); pL.w = f2bf(accL[3] + bbL.w);
      pR.x = f2bf(accR[0] + bbR.x); pR.y = f2bf(accR[1] + bbR.y);
      pR.z = f2bf(accR[2] + bbR.z); pR.w = f2bf(accR[3] + bbR.w);
      *(ushort4*)&xlb[(size_t)node * 576 + c0] = pL;
      *(ushort4*)&xrb[(size_t)node * 576 + c0] = pR;
    }
  }
}

// ---------------------------------------------------------------------------
// Logits v7: 64 edges / 256-thread block, nt-split across the 4 waves.
// ---------------------------------------------------------------------------
__global__ __launch_bounds__(256) void logits_mfma_kernel(
    const unsigned short* __restrict__ EMBb,   // [NE][96]
    const unsigned short* __restrict__ WeTb,   // [576][96]
    const float* __restrict__ attw,            // [576]
    const unsigned short* __restrict__ XLb,    // [NN][576]
    const unsigned short* __restrict__ XRb,    // [NN][576]
    const int* __restrict__ eidx, const int* __restrict__ srcp,
    const int* __restrict__ dstp,
    float* __restrict__ logp) {               // [NE][6] permuted order
  __shared__ __align__(16) unsigned short emb[64][104];
  __shared__ __align__(16) unsigned short eeb[64][200];
  __shared__ int sd[64][2];
  int t = threadIdx.x;
  int p0 = blockIdx.x * 64;
  if (t < 128) sd[t >> 1][t & 1] = (t & 1) ? dstp[p0 + (t >> 1)] : srcp[p0 + (t >> 1)];
  {
    // stage emb: thread t loads edge (t>>2), 24 elems at (t&3)*24 (48B)
    int e = t >> 2, c0 = (t & 3) * 24;
    int erow = eidx[p0 + e];
    const unsigned short* sp = &EMBb[(size_t)erow * 96 + c0];
    *(bf16x8*)&emb[e][c0]      = *(const bf16x8*)&sp[0];
    *(bf16x8*)&emb[e][c0 + 8]  = *(const bf16x8*)&sp[8];
    *(bf16x8*)&emb[e][c0 + 16] = *(const bf16x8*)&sp[16];
  }
  __syncthreads();

  int wave = t >> 6, lane = t & 63;
  int l15 = lane & 15, quad = lane >> 4;
  int el = t >> 2;             // edge (0..63) for combine phase
  int cq = (t & 3) * 24;
  int gsrc = sd[el][0];
  int gdst = sd[el][1];

  for (int hp = 0; hp < 3; hp++) {
    int h0 = hp * 2, h1 = hp * 2 + 1;
    // prefetch gathers for this head-pair (overlap with MFMA phase)
    const unsigned short* xl0 = &XLb[(size_t)gsrc * 576 + h0 * 96 + cq];
    const unsigned short* xr0 = &XRb[(size_t)gdst * 576 + h0 * 96 + cq];
    const unsigned short* xl1 = &XLb[(size_t)gsrc * 576 + h1 * 96 + cq];
    const unsigned short* xr1 = &XRb[(size_t)gdst * 576 + h1 * 96 + cq];
    bf16x8 gl0[3], gr0[3], gl1[3], gr1[3];
#pragma unroll
    for (int c8 = 0; c8 < 3; c8++) {
      gl0[c8] = *(const bf16x8*)&xl0[c8 * 8];
      gr0[c8] = *(const bf16x8*)&xr0[c8 * 8];
      gl1[c8] = *(const bf16x8*)&xl1[c8 * 8];
      gr1[c8] = *(const bf16x8*)&xr1[c8 * 8];
    }
    // ee for heads (h0,h1): wave handles 3 col-tiles x 4 edge-tiles
#pragma unroll
    for (int k = 0; k < 3; k++) {
      int ntg = wave * 3 + k;
      int col = hp * 192 + ntg * 16 + l15;
      const unsigned short* brow = &WeTb[(size_t)col * 96 + quad * 8];
      bf16x8 b0 = *(const bf16x8*)&brow[0];
      bf16x8 b1 = *(const bf16x8*)&brow[32];
      bf16x8 b2 = *(const bf16x8*)&brow[64];
#pragma unroll
      for (int et = 0; et < 4; et++) {
        const unsigned short* ar = &emb[et * 16 + l15][quad * 8];
        bf16x8 a0 = *(const bf16x8*)&ar[0];
        bf16x8 a1 = *(const bf16x8*)&ar[32];
        bf16x8 a2 = *(const bf16x8*)&ar[64];
        f32x4 acc = {0.f, 0.f, 0.f, 0.f};
        acc = __builtin_amdgcn_mfma_f32_16x16x32_bf16(a0, b0, acc, 0, 0, 0);
        acc = __builtin_amdgcn_mfma_f32_16x16x32_bf16(a1, b1, acc, 0, 0, 0);
        acc = __builtin_amdgcn_mfma_f32_16x16x32_bf16(a2, b2, acc, 0, 0, 0);
#pragma unroll
        for (int r = 0; r < 4; r++)
          eeb[et * 16 + quad * 4 + r][ntg * 16 + l15] = f2bf(acc[r]);
      }
    }
    __syncthreads();
    // combine: leaky + attw dot for both heads (4 threads/edge, 24 cols each)
    float pl0 = 0.f, pl1 = 0.f;
    {
      const unsigned short* ee0 = &eeb[el][cq];
      const unsigned short* ee1 = &eeb[el][96 + cq];
      const f32x4* ap0 = (const f32x4*)&attw[h0 * 96 + cq];
      const f32x4* ap1 = (const f32x4*)&attw[h1 * 96 + cq];
#pragma unroll
      for (int c8 = 0; c8 < 3; c8++) {
        bf16x8 ev0 = *(const bf16x8*)&ee0[c8 * 8];
        bf16x8 ev1 = *(const bf16x8*)&ee1[c8 * 8];
        f32x4 a00 = ap0[c8 * 2], a01 = ap0[c8 * 2 + 1];
        f32x4 a10 = ap1[c8 * 2], a11 = ap1[c8 * 2 + 1];
#pragma unroll
        for (int j = 0; j < 4; j++) {
          float v0 = bf2f((unsigned short)ev0[j]) +
                     bf2f((unsigned short)gl0[c8][j]) +
                     bf2f((unsigned short)gr0[c8][j]);
          v0 = (v0 > 0.f) ? v0 : 0.2f * v0;
          pl0 += v0 * a00[j];
          float w0 = bf2f((unsigned short)ev0[j + 4]) +
                     bf2f((unsigned short)gl0[c8][j + 4]) +
                     bf2f((unsigned short)gr0[c8][j + 4]);
          w0 = (w0 > 0.f) ? w0 : 0.2f * w0;
          pl0 += w0 * a01[j];
          float v1 = bf2f((unsigned short)ev1[j]) +
                     bf2f((unsigned short)gl1[c8][j]) +
                     bf2f((unsigned short)gr1[c8][j]);
          v1 = (v1 > 0.f) ? v1 : 0.2f * v1;
          pl1 += v1 * a10[j];
          float w1 = bf2f((unsigned short)ev1[j + 4]) +
                     bf2f((unsigned short)gl1[c8][j + 4]) +
                     bf2f((unsigned short)gr1[c8][j + 4]);
          w1 = (w1 > 0.f) ? w1 : 0.2f * w1;
          pl1 += w1 * a11[j];
        }
      }
    }
    pl0 += __shfl_xor(pl0, 1); pl0 += __shfl_xor(pl0, 2);
    pl1 += __shfl_xor(pl1, 1); pl1 += __shfl_xor(pl1, 2);
    if ((t & 3) == 0) {
      size_t base = (size_t)(p0 + el) * 6 + hp * 2;
      logp[base] = pl0;
      logp[base + 1] = pl1;
    }
    __syncthreads();
  }
}

// ---------------------------------------------------------------------------
// Alpha: wave-per-node segment softmax over dst-sorted logits.
// ---------------------------------------------------------------------------
__global__ __launch_bounds__(256) void alpha_kernel(
    const float* __restrict__ logp, const int* __restrict__ rowptr,
    float* __restrict__ alpha) {
  int node = blockIdx.x * 4 + (threadIdx.x >> 6);
  int lane = threadIdx.x & 63;
  if (node >= NN) return;
  int r0 = rowptr[node], r1 = rowptr[node + 1];
  int d = r1 - r0;
  if (d == 0) return;
  if (d <= 64) {
    bool act = lane < d;
    int p = r0 + (act ? lane : (d - 1));
    float lg[6];
#pragma unroll
    for (int h = 0; h < 6; h++) lg[h] = logp[(size_t)p * 6 + h];
#pragma unroll
    for (int h = 0; h < 6; h++) {
      float m = act ? lg[h] : -1e30f;
#pragma unroll
      for (int off = 32; off > 0; off >>= 1) m = fmaxf(m, __shfl_xor(m, off));
      float w = act ? expf(lg[h] - m) : 0.f;
      float s = w;
#pragma unroll
      for (int off = 32; off > 0; off >>= 1) s += __shfl_xor(s, off);
      if (act) alpha[(size_t)p * 6 + h] = w / (s + 1e-16f);
    }
  } else {
    float m[6], s[6];
#pragma unroll
    for (int h = 0; h < 6; h++) { m[h] = -1e30f; s[h] = 0.f; }
    for (int cs = 0; cs < d; cs += 64) {
      int cnt = min(64, d - cs);
      bool act = lane < cnt;
      int p = r0 + cs + (act ? lane : (cnt - 1));
#pragma unroll
      for (int h = 0; h < 6; h++) {
        float lg = act ? logp[(size_t)p * 6 + h] : -1e30f;
        float cm = lg;
#pragma unroll
        for (int off = 32; off > 0; off >>= 1) cm = fmaxf(cm, __shfl_xor(cm, off));
        float newm = fmaxf(m[h], cm);
        float w = act ? expf(lg - newm) : 0.f;
        float ss = w;
#pragma unroll
        for (int off = 32; off > 0; off >>= 1) ss += __shfl_xor(ss, off);
        s[h] = s[h] * expf(m[h] - newm) + ss;
        m[h] = newm;
      }
    }
    float inv[6];
#pragma unroll
    for (int h = 0; h < 6; h++) inv[h] = 1.f / (s[h] + 1e-16f);
    for (int cs = 0; cs < d; cs += 64) {
      int cnt = min(64, d - cs);
      if (lane < cnt) {
        int p = r0 + cs + lane;
#pragma unroll
        for (int h = 0; h < 6; h++)
          alpha[(size_t)p * 6 + h] =
              expf(logp[(size_t)p * 6 + h] - m[h]) * inv[h];
      }
    }
  }
}

// ---------------------------------------------------------------------------
// Aggregate v5: 8 edge-slots x 72 threads, 16B vector gathers, LDS-staged
// srcp/alpha (breaks the index->gather dependent chain; 8 edges in flight).
// Cross-slot reduce in LDS, then unchanged head-mean + LN + residual.
// ---------------------------------------------------------------------------
__global__ __launch_bounds__(576) void aggregate_kernel(
    float* __restrict__ x, unsigned short* __restrict__ xb,
    const unsigned short* __restrict__ XLb,
    const float* __restrict__ alpha, const int* __restrict__ rowptr,
    const int* __restrict__ srcp,
    const float* __restrict__ cbias, const float* __restrict__ lng,
    const float* __restrict__ lnb, int do_elu) {
  int n = blockIdx.x;
  int t = threadIdx.x;
  int r0 = rowptr[n];
  int d = rowptr[n + 1] - r0;
  __shared__ float scratch[8][584];   // slot-partials, padded row
  __shared__ int sdv[64];
  __shared__ float av[64][6];
  __shared__ float fin[96];
  __shared__ float part[2][2];
  __shared__ float red[2];
  int wave = t >> 6, lane = t & 63;
  int slot = t / 72;          // 0..7
  int c8 = t % 72;
  int ch = c8 * 8;            // channel base (0..568, step 8)
  int h = ch / 96;            // head for this channel group
  float acc[8] = {0.f, 0.f, 0.f, 0.f, 0.f, 0.f, 0.f, 0.f};

  for (int base = 0; base < d; base += 64) {
    int cnt = min(64, d - base);
    if (base > 0) __syncthreads();  // protect restage
    if (t < cnt) sdv[t] = srcp[r0 + base + t];
    if (t >= 64 && t < 64 + cnt * 6) {
      int u = t - 64;
      av[u / 6][u % 6] = alpha[(size_t)(r0 + base + u / 6) * 6 + (u % 6)];
    }
    __syncthreads();
    for (int j = slot; j < cnt; j += 8) {
      float w = av[j][h];
      int s = sdv[j];
      bf16x8 xv = *(const bf16x8*)&XLb[(size_t)s * 576 + ch];
#pragma unroll
      for (int q = 0; q < 8; q++) acc[q] += w * bf2f((unsigned short)xv[q]);
    }
  }
  // write slot partials
  f32x4 a0 = {acc[0], acc[1], acc[2], acc[3]};
  f32x4 a1 = {acc[4], acc[5], acc[6], acc[7]};
  *(f32x4*)&scratch[slot][ch] = a0;
  *(f32x4*)&scratch[slot][ch + 4] = a1;
  __syncthreads();
  // slot reduce: 576 threads each own one channel
  {
    float v = 0.f;
#pragma unroll
    for (int sl = 0; sl < 8; sl++) v += scratch[sl][t];
    __syncthreads();
    scratch[0][t] = v;
  }
  __syncthreads();
  float fv = 0.f;
  if (t < 96) {
    float s = 0.f;
    for (int hh = 0; hh < 6; hh++) s += scratch[0][hh * 96 + t];
    s = s * (1.f / 6.f) + cbias[t];
    if (do_elu) s = (s > 0.f) ? s : expm1f(s);
    fv = s;
    fin[t] = s;
  }
  if (wave < 2) {
    float ps = (t < 96) ? fv : 0.f;
    float ps2 = (t < 96) ? fv * fv : 0.f;
#pragma unroll
    for (int off = 32; off > 0; off >>= 1) {
      ps += __shfl_xor(ps, off);
      ps2 += __shfl_xor(ps2, off);
    }
    if (lane == 0) { part[wave][0] = ps; part[wave][1] = ps2; }
  }
  __syncthreads();
  if (t == 0) {
    float s = part[0][0] + part[1][0];
    float s2 = part[0][1] + part[1][1];
    float mu = s / 96.f;
    float var = s2 / 96.f - mu * mu;
    red[0] = mu; red[1] = rsqrtf(var + 1e-5f);
  }
  __syncthreads();
  if (t < 96) {
    float y = (fin[t] - red[0]) * red[1] * lng[t] + lnb[t];
    float nv = x[(size_t)n * 96 + t] + y;
    x[(size_t)n * 96 + t] = nv;
    xb[(size_t)n * 96 + t] = f2bf(nv);
  }
}

// ---------------------------------------------------------------------------
// Predictor v2: LDS-staged weight panels (fragment-order), 4x L2-traffic cut.
// ---------------------------------------------------------------------------
__global__ __launch_bounds__(256) void pred_mfma_kernel(
    const unsigned short* __restrict__ Xb,     // [NN][96]
    const unsigned short* __restrict__ EMBb,   // [NE][96]
    const int* __restrict__ src, const int* __restrict__ dst,
    const unsigned short* __restrict__ p1wT,   // [128][288]
    const float* __restrict__ p1b, const float* __restrict__ p1g,
    const float* __restrict__ p1be,
    const unsigned short* __restrict__ p2wT,   // [64][128]
    const float* __restrict__ p2b, const float* __restrict__ p2g,
    const float* __restrict__ p2be,
    const float* __restrict__ p3w, const float* __restrict__ p3b,
    float* __restrict__ out) {
  __shared__ __align__(16) unsigned short fragB[4 * 9 * 64 * 8];  // 36,864 B
  __shared__ unsigned short h1s[4][16][136];                      // 17,408 B
  int t = threadIdx.x;
  int wave = t >> 6, lane = t & 63;
  int l15 = lane & 15, quad = lane >> 4;
  int ebase = blockIdx.x * 64 + wave * 16;
  int erow = ebase + l15;
  int sN = src[erow], dN = dst[erow];

  bf16x8 A[9];
  const unsigned short* xs = &Xb[(size_t)sN * 96 + quad * 8];
  const unsigned short* xd = &Xb[(size_t)dN * 96 + quad * 8];
  const unsigned short* em = &EMBb[(size_t)erow * 96 + quad * 8];
#pragma unroll
  for (int c = 0; c < 3; c++) {
    A[c]     = *(const bf16x8*)&xs[c * 32];
    A[c + 3] = *(const bf16x8*)&xd[c * 32];
    A[c + 6] = *(const bf16x8*)&em[c * 32];
  }

  // stage p1wT half-1: wave w stages rows nt=w (cols w*16..w*16+15)
  {
    bf16x8 tmp[9];
#pragma unroll
    for (int c = 0; c < 9; c++)
      tmp[c] = *(const bf16x8*)&p1wT[(size_t)(wave * 16 + l15) * 288 + c * 32 + quad * 8];
#pragma unroll
    for (int c = 0; c < 9; c++)
      *(bf16x8*)&fragB[((wave * 9 + c) * 64 + lane) * 8] = tmp[c];
  }
  __syncthreads();

  f32x4 C1[8];
#pragma unroll
  for (int nt = 0; nt < 4; nt++) {
    f32x4 acc = {0.f, 0.f, 0.f, 0.f};
#pragma unroll
    for (int c = 0; c < 9; c++) {
      bf16x8 B = *(const bf16x8*)&fragB[((nt * 9 + c) * 64 + lane) * 8];
      acc = __builtin_amdgcn_mfma_f32_16x16x32_bf16(A[c], B, acc, 0, 0, 0);
    }
    float bias = p1b[nt * 16 + l15];
    acc[0] += bias; acc[1] += bias; acc[2] += bias; acc[3] += bias;
    C1[nt] = acc;
  }
  __syncthreads();
  // stage p1wT half-2: rows nt=4+w
  {
    bf16x8 tmp[9];
#pragma unroll
    for (int c = 0; c < 9; c++)
      tmp[c] = *(const bf16x8*)&p1wT[(size_t)((4 + wave) * 16 + l15) * 288 + c * 32 + quad * 8];
#pragma unroll
    for (int c = 0; c < 9; c++)
      *(bf16x8*)&fragB[((wave * 9 + c) * 64 + lane) * 8] = tmp[c];
  }
  __syncthreads();
#pragma unroll
  for (int nt = 4; nt < 8; nt++) {
    f32x4 acc = {0.f, 0.f, 0.f, 0.f};
#pragma unroll
    for (int c = 0; c < 9; c++) {
      bf16x8 B = *(const bf16x8*)&fragB[(((nt - 4) * 9 + c) * 64 + lane) * 8];
      acc = __builtin_amdgcn_mfma_f32_16x16x32_bf16(A[c], B, acc, 0, 0, 0);
    }
    float bias = p1b[nt * 16 + l15];
    acc[0] += bias; acc[1] += bias; acc[2] += bias; acc[3] += bias;
    C1[nt] = acc;
  }
  __syncthreads();  // all fragB reads done before layer-2 restage
  // stage p2wT: wave w stages rows nt2=w (overlaps LN math below)
  {
    bf16x8 tmp[4];
#pragma unroll
    for (int c = 0; c < 4; c++)
      tmp[c] = *(const bf16x8*)&p2wT[(size_t)(wave * 16 + l15) * 128 + c * 32 + quad * 8];
#pragma unroll
    for (int c = 0; c < 4; c++)
      *(bf16x8*)&fragB[((wave * 4 + c) * 64 + lane) * 8] = tmp[c];
  }

  float mu1[4], rs1[4];
#pragma unroll
  for (int r = 0; r < 4; r++) {
    float s = 0.f, s2 = 0.f;
#pragma unroll
    for (int nt = 0; nt < 8; nt++) { float v = C1[nt][r]; s += v; s2 += v * v; }
    s += __shfl_xor(s, 1);  s += __shfl_xor(s, 2);
    s += __shfl_xor(s, 4);  s += __shfl_xor(s, 8);
    s2 += __shfl_xor(s2, 1); s2 += __shfl_xor(s2, 2);
    s2 += __shfl_xor(s2, 4); s2 += __shfl_xor(s2, 8);
    float mu = s * (1.f / 128.f);
    float var = s2 * (1.f / 128.f) - mu * mu;
    mu1[r] = mu;
    rs1[r] = rsqrtf(var + 1e-5f);
  }
#pragma unroll
  for (int nt = 0; nt < 8; nt++) {
    float g = p1g[nt * 16 + l15], be = p1be[nt * 16 + l15];
#pragma unroll
    for (int r = 0; r < 4; r++) {
      float v = (C1[nt][r] - mu1[r]) * rs1[r] * g + be;
      v = fmaxf(v, 0.f);
      h1s[wave][quad * 4 + r][nt * 16 + l15] = f2bf(v);
    }
  }
  __syncthreads();  // covers h1s writes AND p2wT staging

  f32x4 C2[4];
#pragma unroll
  for (int nt = 0; nt < 4; nt++) {
    f32x4 acc = {0.f, 0.f, 0.f, 0.f};
#pragma unroll
    for (int c = 0; c < 4; c++) {
      bf16x8 Af = *(const bf16x8*)&h1s[wave][l15][c * 32 + quad * 8];
      bf16x8 B = *(const bf16x8*)&fragB[((nt * 4 + c) * 64 + lane) * 8];
      acc = __builtin_amdgcn_mfma_f32_16x16x32_bf16(Af, B, acc, 0, 0, 0);
    }
    float bias = p2b[nt * 16 + l15];
    acc[0] += bias; acc[1] += bias; acc[2] += bias; acc[3] += bias;
    C2[nt] = acc;
  }

  float mu2[4], rs2[4];
#pragma unroll
  for (int r = 0; r < 4; r++) {
    float s = 0.f, s2 = 0.f;
#pragma unroll
    for (int nt = 0; nt < 4; nt++) { float v = C2[nt][r]; s += v; s2 += v * v; }
    s += __shfl_xor(s, 1);  s += __shfl_xor(s, 2);
    s += __shfl_xor(s, 4);  s += __shfl_xor(s, 8);
    s2 += __shfl_xor(s2, 1); s2 += __shfl_xor(s2, 2);
    s2 += __shfl_xor(s2, 4); s2 += __shfl_xor(s2, 8);
    float mu = s * (1.f / 64.f);
    float var = s2 * (1.f / 64.f) - mu * mu;
    mu2[r] = mu;
    rs2[r] = rsqrtf(var + 1e-5f);
  }

  float partial[4] = {0.f, 0.f, 0.f, 0.f};
#pragma unroll
  for (int nt = 0; nt < 4; nt++) {
    float g = p2g[nt * 16 + l15], be = p2be[nt * 16 + l15];
    float pw = p3w[nt * 16 + l15];
#pragma unroll
    for (int r = 0; r < 4; r++) {
      float v = (C2[nt][r] - mu2[r]) * rs2[r] * g + be;
      v = fmaxf(v, 0.f);
      partial[r] += v * pw;
    }
  }
#pragma unroll
  for (int r = 0; r < 4; r++) {
    float p = partial[r];
    p += __shfl_xor(p, 1);
    p += __shfl_xor(p, 2);
    p += __shfl_xor(p, 4);
    p += __shfl_xor(p, 8);
    partial[r] = p;
  }
  if (l15 == 0) {
    float b3 = p3b[0];
#pragma unroll
    for (int r = 0; r < 4; r++)
      out[ebase + quad * 4 + r] = partial[r] + b3;
  }
}

// ---------------------------------------------------------------------------
static inline size_t alignup(size_t v) { return (v + 255) & ~(size_t)255; }

extern "C" void kernel_launch(void* const* d_in, const int* in_sizes, int n_in,
                              void* d_out, int out_size, void* d_ws, size_t ws_size,
                              hipStream_t stream) {
  const float* x_in      = (const float*)d_in[0];
  const float* edge_attr = (const float*)d_in[1];
  const int*   ei        = (const int*)d_in[2];
  const int* src = ei;
  const int* dst = ei + NE;
  const float* ne_w = (const float*)d_in[3];
  const float* ne_b = (const float*)d_in[4];
  const float* ne_g = (const float*)d_in[5];
  const float* ne_be = (const float*)d_in[6];
  const float* ee_w = (const float*)d_in[7];
  const float* ee_b = (const float*)d_in[8];
  const float* ee_g = (const float*)d_in[9];
  const float* ee_be = (const float*)d_in[10];
  const float* Wl = (const float*)d_in[11];
  const float* bl = (const float*)d_in[12];
  const float* Wr = (const float*)d_in[13];
  const float* br = (const float*)d_in[14];
  const float* We = (const float*)d_in[15];
  const float* attw = (const float*)d_in[16];
  const float* cbias = (const float*)d_in[17];
  const float* lng = (const float*)d_in[18];
  const float* lnb = (const float*)d_in[19];
  const float* p1w = (const float*)d_in[20];
  const float* p1b = (const float*)d_in[21];
  const float* p1g = (const float*)d_in[22];
  const float* p1be = (const float*)d_in[23];
  const float* p2w = (const float*)d_in[24];
  const float* p2b = (const float*)d_in[25];
  const float* p2g = (const float*)d_in[26];
  const float* p2be = (const float*)d_in[27];
  const float* p3w = (const float*)d_in[28];
  const float* p3b = (const float*)d_in[29];
  float* out = (float*)d_out;

  // workspace carve (aligned)
  char* w = (char*)d_ws;
  float* X    = (float*)w; w += alignup((size_t)NN * 96 * 4);
  float* LOG  = (float*)w; w += alignup((size_t)NE * 6 * 4);
  float* ALPHA = (float*)w; w += alignup((size_t)NE * 6 * 4);
  unsigned short* EMBb = (unsigned short*)w; w += alignup((size_t)NE * 96 * 2);
  unsigned short* XLb  = (unsigned short*)w; w += alignup((size_t)NN * 576 * 2);
  unsigned short* XRb  = (unsigned short*)w; w += alignup((size_t)NN * 576 * 2);
  unsigned short* Xb   = (unsigned short*)w; w += alignup((size_t)NN * 96 * 2);
  unsigned short* WeTb = (unsigned short*)w; w += alignup((size_t)3 * 576 * 96 * 2);
  unsigned short* WlTb = (unsigned short*)w; w += alignup((size_t)3 * 576 * 96 * 2);
  unsigned short* WrTb = (unsigned short*)w; w += alignup((size_t)3 * 576 * 96 * 2);
  unsigned short* p1wT = (unsigned short*)w; w += alignup((size_t)128 * 288 * 2);
  unsigned short* p2wT = (unsigned short*)w; w += alignup((size_t)64 * 128 * 2);
  int* deg    = (int*)w; w += alignup((size_t)(NN + 1) * 4);
  int* rowptr = (int*)w; w += alignup((size_t)(NN + 1) * 4);
  int* cursor = (int*)w; w += alignup((size_t)NN * 4);
  int* eidx   = (int*)w; w += alignup((size_t)NE * 4);
  int* srcp   = (int*)w; w += alignup((size_t)NE * 4);
  int* dstp   = (int*)w; w += alignup((size_t)NE * 4);

  // encoders + weight prep
  encode_row_kernel<4><<<(NN + 255) / 256, 256, 0, stream>>>(
      x_in, ne_w, ne_b, ne_g, ne_be, X, Xb, NN);
  encode_row_kernel<3><<<(NE + 255) / 256, 256, 0, stream>>>(
      edge_attr, ee_w, ee_b, ee_g, ee_be, nullptr, EMBb, NE);
  convW_kernel<<<(3 * 576 * 96 + 255) / 256, 256, 0, stream>>>(
      We, WeTb, Wl, WlTb, Wr, WrTb, p1w, p1wT, p2w, p2wT);

  // CSR by dst
  hipMemsetAsync(deg, 0, (size_t)(NN + 1) * 4, stream);
  hist_kernel<<<(NE + 255) / 256, 256, 0, stream>>>(dst, deg);
  scan_kernel<<<1, 1024, 0, stream>>>(deg, rowptr, cursor);
  scatter_kernel<<<(NE + 255) / 256, 256, 0, stream>>>(src, dst, cursor, eidx,
                                                       srcp, dstp);

  // 3 GATv2 layers
  for (int i = 0; i < 3; i++) {
    const unsigned short* WlT_i = WlTb + (size_t)i * 576 * 96;
    const float* bl_i = bl + (size_t)i * 576;
    const unsigned short* WrT_i = WrTb + (size_t)i * 576 * 96;
    const float* br_i = br + (size_t)i * 576;
    const unsigned short* WeT_i = WeTb + (size_t)i * 576 * 96;
    const float* aw_i = attw + (size_t)i * 576;
    const float* cb_i = cbias + (size_t)i * 96;
    const float* lg_i = lng + (size_t)i * 96;
    const float* lb_i = lnb + (size_t)i * 96;
    xlxr_mfma_kernel<<<(NN + 63) / 64, 256, 0, stream>>>(Xb, WlT_i, bl_i,
                                                         WrT_i, br_i, XLb, XRb);
    logits_mfma_kernel<<<NE / 64, 256, 0, stream>>>(EMBb, WeT_i, aw_i, XLb, XRb,
                                                    eidx, srcp, dstp, LOG);
    alpha_kernel<<<(NN + 3) / 4, 256, 0, stream>>>(LOG, rowptr, ALPHA);
    aggregate_kernel<<<NN, 576, 0, stream>>>(X, Xb, XLb, ALPHA, rowptr, srcp,
                                             cb_i, lg_i, lb_i, (i < 2) ? 1 : 0);
  }

  // predictor (MFMA)
  pred_mfma_kernel<<<NE / 64, 256, 0, stream>>>(Xb, EMBb, src, dst,
                                                p1wT, p1b, p1g, p1be,
                                                p2wT, p2b, p2g, p2be,
                                                p3w, p3b, out);
}

// Round 5
// 1003.868 us; speedup vs baseline: 1.0710x; 1.0710x over previous
//
#include <hip/hip_runtime.h>
#include <math.h>

#define NN 20000
#define NE 200000

typedef __attribute__((ext_vector_type(8))) short bf16x8;
typedef __attribute__((ext_vector_type(8))) unsigned short u16x8;
typedef __attribute__((ext_vector_type(4))) float f32x4;

__device__ __forceinline__ unsigned short f2bf(float x) {
  union { float f; unsigned u; } c; c.f = x;
  unsigned r = c.u + 0x7FFF + ((c.u >> 16) & 1);
  return (unsigned short)(r >> 16);
}
__device__ __forceinline__ float bf2f(unsigned short u) {
  union { unsigned u; float f; } c; c.u = ((unsigned)u) << 16;
  return c.f;
}

// ---------------------------------------------------------------------------
// Encoder v2: ONE THREAD PER ROW. out = relu(LN(in @ W + b)).
// ---------------------------------------------------------------------------
template <int D>
__global__ __launch_bounds__(256) void encode_row_kernel(
    const float* __restrict__ in,
    const float* __restrict__ W, const float* __restrict__ b,
    const float* __restrict__ g, const float* __restrict__ beta,
    float* __restrict__ out, unsigned short* __restrict__ outb, int R) {
  int row = blockIdx.x * 256 + threadIdx.x;
  if (row >= R) return;
  float vin[D];
#pragma unroll
  for (int k = 0; k < D; k++) vin[k] = in[(size_t)row * D + k];
  float y[96];
  float s = 0.f, s2 = 0.f;
#pragma unroll
  for (int j = 0; j < 96; j++) {
    float v = b[j];
#pragma unroll
    for (int k = 0; k < D; k++) v += vin[k] * W[k * 96 + j];
    y[j] = v;
    s += v;
    s2 += v * v;
  }
  float mu = s * (1.f / 96.f);
  float var = s2 * (1.f / 96.f) - mu * mu;
  float rs = rsqrtf(var + 1e-5f);
#pragma unroll
  for (int c = 0; c < 12; c++) {
    u16x8 pk;
    float yo[8];
#pragma unroll
    for (int j = 0; j < 8; j++) {
      int jj = c * 8 + j;
      float v = (y[jj] - mu) * rs * g[jj] + beta[jj];
      v = fmaxf(v, 0.f);
      yo[j] = v;
      pk[j] = f2bf(v);
    }
    *(u16x8*)&outb[(size_t)row * 96 + c * 8] = pk;
    if (out) {
      f32x4 o0 = {yo[0], yo[1], yo[2], yo[3]};
      f32x4 o1 = {yo[4], yo[5], yo[6], yo[7]};
      *(f32x4*)&out[(size_t)row * 96 + c * 8] = o0;
      *(f32x4*)&out[(size_t)row * 96 + c * 8 + 4] = o1;
    }
  }
}

// ---------------------------------------------------------------------------
// Weight prep
// ---------------------------------------------------------------------------
__global__ void convW_kernel(const float* __restrict__ We,
                             unsigned short* __restrict__ WeTb,
                             const float* __restrict__ Wl,
                             unsigned short* __restrict__ WlTb,
                             const float* __restrict__ Wr,
                             unsigned short* __restrict__ WrTb,
                             const float* __restrict__ p1w,
                             unsigned short* __restrict__ p1wT,
                             const float* __restrict__ p2w,
                             unsigned short* __restrict__ p2wT) {
  int idx = blockIdx.x * 256 + threadIdx.x;
  if (idx < 3 * 576 * 96) {
    int l = idx / (576 * 96);
    int rem = idx % (576 * 96);
    int n = rem / 96, k = rem % 96;
    size_t sidx = (size_t)l * 96 * 576 + (size_t)k * 576 + n;
    WeTb[idx] = f2bf(We[sidx]);
    WlTb[idx] = f2bf(Wl[sidx]);
    WrTb[idx] = f2bf(Wr[sidx]);
  }
  if (idx < 128 * 288) {
    int n = idx / 288, k = idx % 288;
    p1wT[idx] = f2bf(p1w[(size_t)k * 128 + n]);
  }
  if (idx < 64 * 128) {
    int n = idx / 128, k = idx % 128;
    p2wT[idx] = f2bf(p2w[(size_t)k * 64 + n]);
  }
}

// ---------------------------------------------------------------------------
// CSR build by dst
// ---------------------------------------------------------------------------
__global__ void hist_kernel(const int* __restrict__ dst, int* __restrict__ deg) {
  int e = blockIdx.x * blockDim.x + threadIdx.x;
  if (e < NE) atomicAdd(&deg[dst[e]], 1);
}

// fast scan: 20 nodes/thread serial prefix + wave shfl scan + 16-wave scan
__global__ __launch_bounds__(1024) void scan_kernel(
    const int* __restrict__ deg, int* __restrict__ rowptr, int* __restrict__ cursor) {
  __shared__ int wsum[16];
  int t = threadIdx.x;
  int base = t * 20;
  int loc[20];
  int s = 0;
#pragma unroll
  for (int j = 0; j < 20; j++) {
    int idx = base + j;
    int v = (idx < NN) ? deg[idx] : 0;
    loc[j] = s;
    s += v;
  }
  int lane = t & 63, wv = t >> 6;
  int inc = s;
#pragma unroll
  for (int off = 1; off < 64; off <<= 1) {
    int up = __shfl_up(inc, off);
    if (lane >= off) inc += up;
  }
  if (lane == 63) wsum[wv] = inc;
  __syncthreads();
  if (wv == 0) {
    int wval = (lane < 16) ? wsum[lane] : 0;
#pragma unroll
    for (int off = 1; off < 16; off <<= 1) {
      int up = __shfl_up(wval, off);
      if (lane >= off) wval += up;
    }
    if (lane < 16) wsum[lane] = wval;
  }
  __syncthreads();
  int wbase = (wv > 0) ? wsum[wv - 1] : 0;
  int excl = wbase + inc - s;
#pragma unroll
  for (int j = 0; j < 20; j++) {
    int idx = base + j;
    if (idx < NN) { rowptr[idx] = excl + loc[j]; cursor[idx] = excl + loc[j]; }
  }
  if (t == 0) rowptr[NN] = NE;
}

__global__ void scatter_kernel(const int* __restrict__ src,
                               const int* __restrict__ dst,
                               int* __restrict__ cursor, int* __restrict__ eidx,
                               int* __restrict__ srcp, int* __restrict__ dstp) {
  int e = blockIdx.x * blockDim.x + threadIdx.x;
  if (e < NE) {
    int d = dst[e];
    int p = atomicAdd(&cursor[d], 1);
    eidx[p] = e;
    srcp[p] = src[e];
    dstp[p] = d;
  }
}

// ---------------------------------------------------------------------------
// xlxr via MFMA (verified R8)
// ---------------------------------------------------------------------------
__global__ __launch_bounds__(256) void xlxr_mfma_kernel(
    const unsigned short* __restrict__ Xb,    // [NN][96]
    const unsigned short* __restrict__ WlTb,  // [576][96]
    const float* __restrict__ bl,
    const unsigned short* __restrict__ WrTb,  // [576][96]
    const float* __restrict__ br,
    unsigned short* __restrict__ xlb, unsigned short* __restrict__ xrb) {
  int t = threadIdx.x;
  int wave = t >> 6, lane = t & 63;
  int l15 = lane & 15, quad = lane >> 4;
  int node = blockIdx.x * 64 + wave * 16 + l15;
  int nclamp = (node < NN) ? node : (NN - 1);
  bool valid = node < NN;
  const unsigned short* brow = &Xb[(size_t)nclamp * 96 + quad * 8];
  bf16x8 b0 = *(const bf16x8*)&brow[0];
  bf16x8 b1 = *(const bf16x8*)&brow[32];
  bf16x8 b2 = *(const bf16x8*)&brow[64];
#pragma unroll
  for (int mt = 0; mt < 36; mt++) {
    int wc = mt * 16 + l15;
    const unsigned short* aL = &WlTb[(size_t)wc * 96 + quad * 8];
    f32x4 accL = {0.f, 0.f, 0.f, 0.f};
    accL = __builtin_amdgcn_mfma_f32_16x16x32_bf16(*(const bf16x8*)&aL[0], b0, accL, 0, 0, 0);
    accL = __builtin_amdgcn_mfma_f32_16x16x32_bf16(*(const bf16x8*)&aL[32], b1, accL, 0, 0, 0);
    accL = __builtin_amdgcn_mfma_f32_16x16x32_bf16(*(const bf16x8*)&aL[64], b2, accL, 0, 0, 0);
    const unsigned short* aR = &WrTb[(size_t)wc * 96 + quad * 8];
    f32x4 accR = {0.f, 0.f, 0.f, 0.f};
    accR = __builtin_amdgcn_mfma_f32_16x16x32_bf16(*(const bf16x8*)&aR[0], b0, accR, 0, 0, 0);
    accR = __builtin_amdgcn_mfma_f32_16x16x32_bf16(*(const bf16x8*)&aR[32], b1, accR, 0, 0, 0);
    accR = __builtin_amdgcn_mfma_f32_16x16x32_bf16(*(const bf16x8*)&aR[64], b2, accR, 0, 0, 0);
    if (valid) {
      int c0 = mt * 16 + quad * 4;
      float4 bbL = *(const float4*)&bl[c0];
      float4 bbR = *(const float4*)&br[c0];
      ushort4 pL, pR;
      pL.x = f2bf(accL[0] + bbL.x); pL.y = f2bf(accL[1] + bbL.y);
      pL.z = f2bf(accL[2] + bbL.z); pL.w = f2bf(accL[3] + bbL.w);
      pR.x = f2bf(accR[0] + bbR.x); pR.y = f2bf(accR[1] + bbR.y);
      pR.z = f2bf(accR[2] + bbR.z); pR.w = f2bf(accR[3] + bbR.w);
      *(ushort4*)&xlb[(size_t)node * 576 + c0] = pL;
      *(ushort4*)&xrb[(size_t)node * 576 + c0] = pR;
    }
  }
}

// ---------------------------------------------------------------------------
// Logits v7: 64 edges / 256-thread block, nt-split across the 4 waves.
// ---------------------------------------------------------------------------
__global__ __launch_bounds__(256) void logits_mfma_kernel(
    const unsigned short* __restrict__ EMBb,   // [NE][96]
    const unsigned short* __restrict__ WeTb,   // [576][96]
    const float* __restrict__ attw,            // [576]
    const unsigned short* __restrict__ XLb,    // [NN][576]
    const unsigned short* __restrict__ XRb,    // [NN][576]
    const int* __restrict__ eidx, const int* __restrict__ srcp,
    const int* __restrict__ dstp,
    float* __restrict__ logp) {               // [NE][6] permuted order
  __shared__ __align__(16) unsigned short emb[64][104];
  __shared__ __align__(16) unsigned short eeb[64][200];
  __shared__ int sd[64][2];
  int t = threadIdx.x;
  int p0 = blockIdx.x * 64;
  if (t < 128) sd[t >> 1][t & 1] = (t & 1) ? dstp[p0 + (t >> 1)] : srcp[p0 + (t >> 1)];
  {
    // stage emb: thread t loads edge (t>>2), 24 elems at (t&3)*24 (48B)
    int e = t >> 2, c0 = (t & 3) * 24;
    int erow = eidx[p0 + e];
    const unsigned short* sp = &EMBb[(size_t)erow * 96 + c0];
    *(bf16x8*)&emb[e][c0]      = *(const bf16x8*)&sp[0];
    *(bf16x8*)&emb[e][c0 + 8]  = *(const bf16x8*)&sp[8];
    *(bf16x8*)&emb[e][c0 + 16] = *(const bf16x8*)&sp[16];
  }
  __syncthreads();

  int wave = t >> 6, lane = t & 63;
  int l15 = lane & 15, quad = lane >> 4;
  int el = t >> 2;             // edge (0..63) for combine phase
  int cq = (t & 3) * 24;
  int gsrc = sd[el][0];
  int gdst = sd[el][1];

  for (int hp = 0; hp < 3; hp++) {
    int h0 = hp * 2, h1 = hp * 2 + 1;
    // prefetch gathers for this head-pair (overlap with MFMA phase)
    const unsigned short* xl0 = &XLb[(size_t)gsrc * 576 + h0 * 96 + cq];
    const unsigned short* xr0 = &XRb[(size_t)gdst * 576 + h0 * 96 + cq];
    const unsigned short* xl1 = &XLb[(size_t)gsrc * 576 + h1 * 96 + cq];
    const unsigned short* xr1 = &XRb[(size_t)gdst * 576 + h1 * 96 + cq];
    bf16x8 gl0[3], gr0[3], gl1[3], gr1[3];
#pragma unroll
    for (int c8 = 0; c8 < 3; c8++) {
      gl0[c8] = *(const bf16x8*)&xl0[c8 * 8];
      gr0[c8] = *(const bf16x8*)&xr0[c8 * 8];
      gl1[c8] = *(const bf16x8*)&xl1[c8 * 8];
      gr1[c8] = *(const bf16x8*)&xr1[c8 * 8];
    }
    // ee for heads (h0,h1): wave handles 3 col-tiles x 4 edge-tiles
#pragma unroll
    for (int k = 0; k < 3; k++) {
      int ntg = wave * 3 + k;
      int col = hp * 192 + ntg * 16 + l15;
      const unsigned short* brow = &WeTb[(size_t)col * 96 + quad * 8];
      bf16x8 b0 = *(const bf16x8*)&brow[0];
      bf16x8 b1 = *(const bf16x8*)&brow[32];
      bf16x8 b2 = *(const bf16x8*)&brow[64];
#pragma unroll
      for (int et = 0; et < 4; et++) {
        const unsigned short* ar = &emb[et * 16 + l15][quad * 8];
        bf16x8 a0 = *(const bf16x8*)&ar[0];
        bf16x8 a1 = *(const bf16x8*)&ar[32];
        bf16x8 a2 = *(const bf16x8*)&ar[64];
        f32x4 acc = {0.f, 0.f, 0.f, 0.f};
        acc = __builtin_amdgcn_mfma_f32_16x16x32_bf16(a0, b0, acc, 0, 0, 0);
        acc = __builtin_amdgcn_mfma_f32_16x16x32_bf16(a1, b1, acc, 0, 0, 0);
        acc = __builtin_amdgcn_mfma_f32_16x16x32_bf16(a2, b2, acc, 0, 0, 0);
#pragma unroll
        for (int r = 0; r < 4; r++)
          eeb[et * 16 + quad * 4 + r][ntg * 16 + l15] = f2bf(acc[r]);
      }
    }
    __syncthreads();
    // combine: leaky + attw dot for both heads (4 threads/edge, 24 cols each)
    float pl0 = 0.f, pl1 = 0.f;
    {
      const unsigned short* ee0 = &eeb[el][cq];
      const unsigned short* ee1 = &eeb[el][96 + cq];
      const f32x4* ap0 = (const f32x4*)&attw[h0 * 96 + cq];
      const f32x4* ap1 = (const f32x4*)&attw[h1 * 96 + cq];
#pragma unroll
      for (int c8 = 0; c8 < 3; c8++) {
        bf16x8 ev0 = *(const bf16x8*)&ee0[c8 * 8];
        bf16x8 ev1 = *(const bf16x8*)&ee1[c8 * 8];
        f32x4 a00 = ap0[c8 * 2], a01 = ap0[c8 * 2 + 1];
        f32x4 a10 = ap1[c8 * 2], a11 = ap1[c8 * 2 + 1];
#pragma unroll
        for (int j = 0; j < 4; j++) {
          float v0 = bf2f((unsigned short)ev0[j]) +
                     bf2f((unsigned short)gl0[c8][j]) +
                     bf2f((unsigned short)gr0[c8][j]);
          v0 = (v0 > 0.f) ? v0 : 0.2f * v0;
          pl0 += v0 * a00[j];
          float w0 = bf2f((unsigned short)ev0[j + 4]) +
                     bf2f((unsigned short)gl0[c8][j + 4]) +
                     bf2f((unsigned short)gr0[c8][j + 4]);
          w0 = (w0 > 0.f) ? w0 : 0.2f * w0;
          pl0 += w0 * a01[j];
          float v1 = bf2f((unsigned short)ev1[j]) +
                     bf2f((unsigned short)gl1[c8][j]) +
                     bf2f((unsigned short)gr1[c8][j]);
          v1 = (v1 > 0.f) ? v1 : 0.2f * v1;
          pl1 += v1 * a10[j];
          float w1 = bf2f((unsigned short)ev1[j + 4]) +
                     bf2f((unsigned short)gl1[c8][j + 4]) +
                     bf2f((unsigned short)gr1[c8][j + 4]);
          w1 = (w1 > 0.f) ? w1 : 0.2f * w1;
          pl1 += w1 * a11[j];
        }
      }
    }
    pl0 += __shfl_xor(pl0, 1); pl0 += __shfl_xor(pl0, 2);
    pl1 += __shfl_xor(pl1, 1); pl1 += __shfl_xor(pl1, 2);
    if ((t & 3) == 0) {
      size_t base = (size_t)(p0 + el) * 6 + hp * 2;
      logp[base] = pl0;
      logp[base + 1] = pl1;
    }
    __syncthreads();
  }
}

// ---------------------------------------------------------------------------
// Alpha: wave-per-node segment softmax over dst-sorted logits.
// ---------------------------------------------------------------------------
__global__ __launch_bounds__(256) void alpha_kernel(
    const float* __restrict__ logp, const int* __restrict__ rowptr,
    float* __restrict__ alpha) {
  int node = blockIdx.x * 4 + (threadIdx.x >> 6);
  int lane = threadIdx.x & 63;
  if (node >= NN) return;
  int r0 = rowptr[node], r1 = rowptr[node + 1];
  int d = r1 - r0;
  if (d == 0) return;
  if (d <= 64) {
    bool act = lane < d;
    int p = r0 + (act ? lane : (d - 1));
    float lg[6];
#pragma unroll
    for (int h = 0; h < 6; h++) lg[h] = logp[(size_t)p * 6 + h];
#pragma unroll
    for (int h = 0; h < 6; h++) {
      float m = act ? lg[h] : -1e30f;
#pragma unroll
      for (int off = 32; off > 0; off >>= 1) m = fmaxf(m, __shfl_xor(m, off));
      float w = act ? expf(lg[h] - m) : 0.f;
      float s = w;
#pragma unroll
      for (int off = 32; off > 0; off >>= 1) s += __shfl_xor(s, off);
      if (act) alpha[(size_t)p * 6 + h] = w / (s + 1e-16f);
    }
  } else {
    float m[6], s[6];
#pragma unroll
    for (int h = 0; h < 6; h++) { m[h] = -1e30f; s[h] = 0.f; }
    for (int cs = 0; cs < d; cs += 64) {
      int cnt = min(64, d - cs);
      bool act = lane < cnt;
      int p = r0 + cs + (act ? lane : (cnt - 1));
#pragma unroll
      for (int h = 0; h < 6; h++) {
        float lg = act ? logp[(size_t)p * 6 + h] : -1e30f;
        float cm = lg;
#pragma unroll
        for (int off = 32; off > 0; off >>= 1) cm = fmaxf(cm, __shfl_xor(cm, off));
        float newm = fmaxf(m[h], cm);
        float w = act ? expf(lg - newm) : 0.f;
        float ss = w;
#pragma unroll
        for (int off = 32; off > 0; off >>= 1) ss += __shfl_xor(ss, off);
        s[h] = s[h] * expf(m[h] - newm) + ss;
        m[h] = newm;
      }
    }
    float inv[6];
#pragma unroll
    for (int h = 0; h < 6; h++) inv[h] = 1.f / (s[h] + 1e-16f);
    for (int cs = 0; cs < d; cs += 64) {
      int cnt = min(64, d - cs);
      if (lane < cnt) {
        int p = r0 + cs + lane;
#pragma unroll
        for (int h = 0; h < 6; h++)
          alpha[(size_t)p * 6 + h] =
              expf(logp[(size_t)p * 6 + h] - m[h]) * inv[h];
      }
    }
  }
}

// ---------------------------------------------------------------------------
// Aggregate v6: v4 structure (no in-loop barriers/LDS) + doubled ILP.
// Block = 576 threads; half 0 (t<288) takes even edges, half 1 odd edges;
// each thread owns 2 channels via one ushort2 (4B) gather. Per edge: 288
// 4B loads (vs 576 2B); serial chain length d/2 per half, 4x unrolled ->
// 8 gathers in flight per channel pair. Partials merge via scratch[2][576].
// ---------------------------------------------------------------------------
__global__ __launch_bounds__(576) void aggregate_kernel(
    float* __restrict__ x, unsigned short* __restrict__ xb,
    const unsigned short* __restrict__ XLb,
    const float* __restrict__ alpha, const int* __restrict__ rowptr,
    const int* __restrict__ srcp,
    const float* __restrict__ cbias, const float* __restrict__ lng,
    const float* __restrict__ lnb, int do_elu) {
  int n = blockIdx.x;
  int t = threadIdx.x;
  int r0 = rowptr[n];
  int d = rowptr[n + 1] - r0;
  __shared__ float scratch[2][576];
  __shared__ float fin[96];
  __shared__ float part[2][2];
  __shared__ float red[2];
  int wave = t >> 6, lane = t & 63;
  int half = (t >= 288) ? 1 : 0;
  int c2 = t - half * 288;
  int ch = c2 * 2;            // channel pair base (same head: 96 is even)
  int h = ch / 96;
  float a0 = 0.f, a1 = 0.f;
  int j = half;
  for (; j + 6 < d; j += 8) {  // edges j, j+2, j+4, j+6 for this half
    int p = r0 + j;
    float w0 = alpha[(size_t)(p + 0) * 6 + h];
    float w1 = alpha[(size_t)(p + 2) * 6 + h];
    float w2 = alpha[(size_t)(p + 4) * 6 + h];
    float w3 = alpha[(size_t)(p + 6) * 6 + h];
    int s0 = srcp[p + 0], s1 = srcp[p + 2];
    int s2 = srcp[p + 4], s3 = srcp[p + 6];
    ushort2 x0 = *(const ushort2*)&XLb[(size_t)s0 * 576 + ch];
    ushort2 x1 = *(const ushort2*)&XLb[(size_t)s1 * 576 + ch];
    ushort2 x2 = *(const ushort2*)&XLb[(size_t)s2 * 576 + ch];
    ushort2 x3 = *(const ushort2*)&XLb[(size_t)s3 * 576 + ch];
    a0 += w0 * bf2f(x0.x) + w1 * bf2f(x1.x) + w2 * bf2f(x2.x) + w3 * bf2f(x3.x);
    a1 += w0 * bf2f(x0.y) + w1 * bf2f(x1.y) + w2 * bf2f(x2.y) + w3 * bf2f(x3.y);
  }
  for (; j < d; j += 2) {
    int p = r0 + j;
    float w = alpha[(size_t)p * 6 + h];
    ushort2 xv = *(const ushort2*)&XLb[(size_t)srcp[p] * 576 + ch];
    a0 += w * bf2f(xv.x);
    a1 += w * bf2f(xv.y);
  }
  scratch[half][ch] = a0;
  scratch[half][ch + 1] = a1;
  __syncthreads();
  float fv = 0.f;
  if (t < 96) {
    float s = 0.f;
    for (int hh = 0; hh < 6; hh++)
      s += scratch[0][hh * 96 + t] + scratch[1][hh * 96 + t];
    s = s * (1.f / 6.f) + cbias[t];
    if (do_elu) s = (s > 0.f) ? s : expm1f(s);
    fv = s;
    fin[t] = s;
  }
  if (wave < 2) {
    float ps = (t < 96) ? fv : 0.f;
    float ps2 = (t < 96) ? fv * fv : 0.f;
#pragma unroll
    for (int off = 32; off > 0; off >>= 1) {
      ps += __shfl_xor(ps, off);
      ps2 += __shfl_xor(ps2, off);
    }
    if (lane == 0) { part[wave][0] = ps; part[wave][1] = ps2; }
  }
  __syncthreads();
  if (t == 0) {
    float s = part[0][0] + part[1][0];
    float s2 = part[0][1] + part[1][1];
    float mu = s / 96.f;
    float var = s2 / 96.f - mu * mu;
    red[0] = mu; red[1] = rsqrtf(var + 1e-5f);
  }
  __syncthreads();
  if (t < 96) {
    float y = (fin[t] - red[0]) * red[1] * lng[t] + lnb[t];
    float nv = x[(size_t)n * 96 + t] + y;
    x[(size_t)n * 96 + t] = nv;
    xb[(size_t)n * 96 + t] = f2bf(nv);
  }
}

// ---------------------------------------------------------------------------
// Predictor v2: LDS-staged weight panels (fragment-order), 4x L2-traffic cut.
// ---------------------------------------------------------------------------
__global__ __launch_bounds__(256) void pred_mfma_kernel(
    const unsigned short* __restrict__ Xb,     // [NN][96]
    const unsigned short* __restrict__ EMBb,   // [NE][96]
    const int* __restrict__ src, const int* __restrict__ dst,
    const unsigned short* __restrict__ p1wT,   // [128][288]
    const float* __restrict__ p1b, const float* __restrict__ p1g,
    const float* __restrict__ p1be,
    const unsigned short* __restrict__ p2wT,   // [64][128]
    const float* __restrict__ p2b, const float* __restrict__ p2g,
    const float* __restrict__ p2be,
    const float* __restrict__ p3w, const float* __restrict__ p3b,
    float* __restrict__ out) {
  __shared__ __align__(16) unsigned short fragB[4 * 9 * 64 * 8];  // 36,864 B
  __shared__ unsigned short h1s[4][16][136];                      // 17,408 B
  int t = threadIdx.x;
  int wave = t >> 6, lane = t & 63;
  int l15 = lane & 15, quad = lane >> 4;
  int ebase = blockIdx.x * 64 + wave * 16;
  int erow = ebase + l15;
  int sN = src[erow], dN = dst[erow];

  bf16x8 A[9];
  const unsigned short* xs = &Xb[(size_t)sN * 96 + quad * 8];
  const unsigned short* xd = &Xb[(size_t)dN * 96 + quad * 8];
  const unsigned short* em = &EMBb[(size_t)erow * 96 + quad * 8];
#pragma unroll
  for (int c = 0; c < 3; c++) {
    A[c]     = *(const bf16x8*)&xs[c * 32];
    A[c + 3] = *(const bf16x8*)&xd[c * 32];
    A[c + 6] = *(const bf16x8*)&em[c * 32];
  }

  // stage p1wT half-1: wave w stages rows nt=w (cols w*16..w*16+15)
  {
    bf16x8 tmp[9];
#pragma unroll
    for (int c = 0; c < 9; c++)
      tmp[c] = *(const bf16x8*)&p1wT[(size_t)(wave * 16 + l15) * 288 + c * 32 + quad * 8];
#pragma unroll
    for (int c = 0; c < 9; c++)
      *(bf16x8*)&fragB[((wave * 9 + c) * 64 + lane) * 8] = tmp[c];
  }
  __syncthreads();

  f32x4 C1[8];
#pragma unroll
  for (int nt = 0; nt < 4; nt++) {
    f32x4 acc = {0.f, 0.f, 0.f, 0.f};
#pragma unroll
    for (int c = 0; c < 9; c++) {
      bf16x8 B = *(const bf16x8*)&fragB[((nt * 9 + c) * 64 + lane) * 8];
      acc = __builtin_amdgcn_mfma_f32_16x16x32_bf16(A[c], B, acc, 0, 0, 0);
    }
    float bias = p1b[nt * 16 + l15];
    acc[0] += bias; acc[1] += bias; acc[2] += bias; acc[3] += bias;
    C1[nt] = acc;
  }
  __syncthreads();
  // stage p1wT half-2: rows nt=4+w
  {
    bf16x8 tmp[9];
#pragma unroll
    for (int c = 0; c < 9; c++)
      tmp[c] = *(const bf16x8*)&p1wT[(size_t)((4 + wave) * 16 + l15) * 288 + c * 32 + quad * 8];
#pragma unroll
    for (int c = 0; c < 9; c++)
      *(bf16x8*)&fragB[((wave * 9 + c) * 64 + lane) * 8] = tmp[c];
  }
  __syncthreads();
#pragma unroll
  for (int nt = 4; nt < 8; nt++) {
    f32x4 acc = {0.f, 0.f, 0.f, 0.f};
#pragma unroll
    for (int c = 0; c < 9; c++) {
      bf16x8 B = *(const bf16x8*)&fragB[(((nt - 4) * 9 + c) * 64 + lane) * 8];
      acc = __builtin_amdgcn_mfma_f32_16x16x32_bf16(A[c], B, acc, 0, 0, 0);
    }
    float bias = p1b[nt * 16 + l15];
    acc[0] += bias; acc[1] += bias; acc[2] += bias; acc[3] += bias;
    C1[nt] = acc;
  }
  __syncthreads();  // all fragB reads done before layer-2 restage
  // stage p2wT: wave w stages rows nt2=w (overlaps LN math below)
  {
    bf16x8 tmp[4];
#pragma unroll
    for (int c = 0; c < 4; c++)
      tmp[c] = *(const bf16x8*)&p2wT[(size_t)(wave * 16 + l15) * 128 + c * 32 + quad * 8];
#pragma unroll
    for (int c = 0; c < 4; c++)
      *(bf16x8*)&fragB[((wave * 4 + c) * 64 + lane) * 8] = tmp[c];
  }

  float mu1[4], rs1[4];
#pragma unroll
  for (int r = 0; r < 4; r++) {
    float s = 0.f, s2 = 0.f;
#pragma unroll
    for (int nt = 0; nt < 8; nt++) { float v = C1[nt][r]; s += v; s2 += v * v; }
    s += __shfl_xor(s, 1);  s += __shfl_xor(s, 2);
    s += __shfl_xor(s, 4);  s += __shfl_xor(s, 8);
    s2 += __shfl_xor(s2, 1); s2 += __shfl_xor(s2, 2);
    s2 += __shfl_xor(s2, 4); s2 += __shfl_xor(s2, 8);
    float mu = s * (1.f / 128.f);
    float var = s2 * (1.f / 128.f) - mu * mu;
    mu1[r] = mu;
    rs1[r] = rsqrtf(var + 1e-5f);
  }
#pragma unroll
  for (int nt = 0; nt < 8; nt++) {
    float g = p1g[nt * 16 + l15], be = p1be[nt * 16 + l15];
#pragma unroll
    for (int r = 0; r < 4; r++) {
      float v = (C1[nt][r] - mu1[r]) * rs1[r] * g + be;
      v = fmaxf(v, 0.f);
      h1s[wave][quad * 4 + r][nt * 16 + l15] = f2bf(v);
    }
  }
  __syncthreads();  // covers h1s writes AND p2wT staging

  f32x4 C2[4];
#pragma unroll
  for (int nt = 0; nt < 4; nt++) {
    f32x4 acc = {0.f, 0.f, 0.f, 0.f};
#pragma unroll
    for (int c = 0; c < 4; c++) {
      bf16x8 Af = *(const bf16x8*)&h1s[wave][l15][c * 32 + quad * 8];
      bf16x8 B = *(const bf16x8*)&fragB[((nt * 4 + c) * 64 + lane) * 8];
      acc = __builtin_amdgcn_mfma_f32_16x16x32_bf16(Af, B, acc, 0, 0, 0);
    }
    float bias = p2b[nt * 16 + l15];
    acc[0] += bias; acc[1] += bias; acc[2] += bias; acc[3] += bias;
    C2[nt] = acc;
  }

  float mu2[4], rs2[4];
#pragma unroll
  for (int r = 0; r < 4; r++) {
    float s = 0.f, s2 = 0.f;
#pragma unroll
    for (int nt = 0; nt < 4; nt++) { float v = C2[nt][r]; s += v; s2 += v * v; }
    s += __shfl_xor(s, 1);  s += __shfl_xor(s, 2);
    s += __shfl_xor(s, 4);  s += __shfl_xor(s, 8);
    s2 += __shfl_xor(s2, 1); s2 += __shfl_xor(s2, 2);
    s2 += __shfl_xor(s2, 4); s2 += __shfl_xor(s2, 8);
    float mu = s * (1.f / 64.f);
    float var = s2 * (1.f / 64.f) - mu * mu;
    mu2[r] = mu;
    rs2[r] = rsqrtf(var + 1e-5f);
  }

  float partial[4] = {0.f, 0.f, 0.f, 0.f};
#pragma unroll
  for (int nt = 0; nt < 4; nt++) {
    float g = p2g[nt * 16 + l15], be = p2be[nt * 16 + l15];
    float pw = p3w[nt * 16 + l15];
#pragma unroll
    for (int r = 0; r < 4; r++) {
      float v = (C2[nt][r] - mu2[r]) * rs2[r] * g + be;
      v = fmaxf(v, 0.f);
      partial[r] += v * pw;
    }
  }
#pragma unroll
  for (int r = 0; r < 4; r++) {
    float p = partial[r];
    p += __shfl_xor(p, 1);
    p += __shfl_xor(p, 2);
    p += __shfl_xor(p, 4);
    p += __shfl_xor(p, 8);
    partial[r] = p;
  }
  if (l15 == 0) {
    float b3 = p3b[0];
#pragma unroll
    for (int r = 0; r < 4; r++)
      out[ebase + quad * 4 + r] = partial[r] + b3;
  }
}

// ---------------------------------------------------------------------------
static inline size_t alignup(size_t v) { return (v + 255) & ~(size_t)255; }

extern "C" void kernel_launch(void* const* d_in, const int* in_sizes, int n_in,
                              void* d_out, int out_size, void* d_ws, size_t ws_size,
                              hipStream_t stream) {
  const float* x_in      = (const float*)d_in[0];
  const float* edge_attr = (const float*)d_in[1];
  const int*   ei        = (const int*)d_in[2];
  const int* src = ei;
  const int* dst = ei + NE;
  const float* ne_w = (const float*)d_in[3];
  const float* ne_b = (const float*)d_in[4];
  const float* ne_g = (const float*)d_in[5];
  const float* ne_be = (const float*)d_in[6];
  const float* ee_w = (const float*)d_in[7];
  const float* ee_b = (const float*)d_in[8];
  const float* ee_g = (const float*)d_in[9];
  const float* ee_be = (const float*)d_in[10];
  const float* Wl = (const float*)d_in[11];
  const float* bl = (const float*)d_in[12];
  const float* Wr = (const float*)d_in[13];
  const float* br = (const float*)d_in[14];
  const float* We = (const float*)d_in[15];
  const float* attw = (const float*)d_in[16];
  const float* cbias = (const float*)d_in[17];
  const float* lng = (const float*)d_in[18];
  const float* lnb = (const float*)d_in[19];
  const float* p1w = (const float*)d_in[20];
  const float* p1b = (const float*)d_in[21];
  const float* p1g = (const float*)d_in[22];
  const float* p1be = (const float*)d_in[23];
  const float* p2w = (const float*)d_in[24];
  const float* p2b = (const float*)d_in[25];
  const float* p2g = (const float*)d_in[26];
  const float* p2be = (const float*)d_in[27];
  const float* p3w = (const float*)d_in[28];
  const float* p3b = (const float*)d_in[29];
  float* out = (float*)d_out;

  // workspace carve (aligned)
  char* w = (char*)d_ws;
  float* X    = (float*)w; w += alignup((size_t)NN * 96 * 4);
  float* LOG  = (float*)w; w += alignup((size_t)NE * 6 * 4);
  float* ALPHA = (float*)w; w += alignup((size_t)NE * 6 * 4);
  unsigned short* EMBb = (unsigned short*)w; w += alignup((size_t)NE * 96 * 2);
  unsigned short* XLb  = (unsigned short*)w; w += alignup((size_t)NN * 576 * 2);
  unsigned short* XRb  = (unsigned short*)w; w += alignup((size_t)NN * 576 * 2);
  unsigned short* Xb   = (unsigned short*)w; w += alignup((size_t)NN * 96 * 2);
  unsigned short* WeTb = (unsigned short*)w; w += alignup((size_t)3 * 576 * 96 * 2);
  unsigned short* WlTb = (unsigned short*)w; w += alignup((size_t)3 * 576 * 96 * 2);
  unsigned short* WrTb = (unsigned short*)w; w += alignup((size_t)3 * 576 * 96 * 2);
  unsigned short* p1wT = (unsigned short*)w; w += alignup((size_t)128 * 288 * 2);
  unsigned short* p2wT = (unsigned short*)w; w += alignup((size_t)64 * 128 * 2);
  int* deg    = (int*)w; w += alignup((size_t)(NN + 1) * 4);
  int* rowptr = (int*)w; w += alignup((size_t)(NN + 1) * 4);
  int* cursor = (int*)w; w += alignup((size_t)NN * 4);
  int* eidx   = (int*)w; w += alignup((size_t)NE * 4);
  int* srcp   = (int*)w; w += alignup((size_t)NE * 4);
  int* dstp   = (int*)w; w += alignup((size_t)NE * 4);

  // encoders + weight prep
  encode_row_kernel<4><<<(NN + 255) / 256, 256, 0, stream>>>(
      x_in, ne_w, ne_b, ne_g, ne_be, X, Xb, NN);
  encode_row_kernel<3><<<(NE + 255) / 256, 256, 0, stream>>>(
      edge_attr, ee_w, ee_b, ee_g, ee_be, nullptr, EMBb, NE);
  convW_kernel<<<(3 * 576 * 96 + 255) / 256, 256, 0, stream>>>(
      We, WeTb, Wl, WlTb, Wr, WrTb, p1w, p1wT, p2w, p2wT);

  // CSR by dst
  hipMemsetAsync(deg, 0, (size_t)(NN + 1) * 4, stream);
  hist_kernel<<<(NE + 255) / 256, 256, 0, stream>>>(dst, deg);
  scan_kernel<<<1, 1024, 0, stream>>>(deg, rowptr, cursor);
  scatter_kernel<<<(NE + 255) / 256, 256, 0, stream>>>(src, dst, cursor, eidx,
                                                       srcp, dstp);

  // 3 GATv2 layers
  for (int i = 0; i < 3; i++) {
    const unsigned short* WlT_i = WlTb + (size_t)i * 576 * 96;
    const float* bl_i = bl + (size_t)i * 576;
    const unsigned short* WrT_i = WrTb + (size_t)i * 576 * 96;
    const float* br_i = br + (size_t)i * 576;
    const unsigned short* WeT_i = WeTb + (size_t)i * 576 * 96;
    const float* aw_i = attw + (size_t)i * 576;
    const float* cb_i = cbias + (size_t)i * 96;
    const float* lg_i = lng + (size_t)i * 96;
    const float* lb_i = lnb + (size_t)i * 96;
    xlxr_mfma_kernel<<<(NN + 63) / 64, 256, 0, stream>>>(Xb, WlT_i, bl_i,
                                                         WrT_i, br_i, XLb, XRb);
    logits_mfma_kernel<<<NE / 64, 256, 0, stream>>>(EMBb, WeT_i, aw_i, XLb, XRb,
                                                    eidx, srcp, dstp, LOG);
    alpha_kernel<<<(NN + 3) / 4, 256, 0, stream>>>(LOG, rowptr, ALPHA);
    aggregate_kernel<<<NN, 576, 0, stream>>>(X, Xb, XLb, ALPHA, rowptr, srcp,
                                             cb_i, lg_i, lb_i, (i < 2) ? 1 : 0);
  }

  // predictor (MFMA)
  pred_mfma_kernel<<<NE / 64, 256, 0, stream>>>(Xb, EMBb, src, dst,
                                                p1wT, p1b, p1g, p1be,
                                                p2wT, p2b, p2g, p2be,
                                                p3w, p3b, out);
}

// Round 6
// 864.597 us; speedup vs baseline: 1.2435x; 1.1611x over previous
//
#include <hip/hip_runtime.h>
#include <math.h>

#define NN 20000
#define NE 200000

typedef __attribute__((ext_vector_type(8))) short bf16x8;
typedef __attribute__((ext_vector_type(8))) unsigned short u16x8;
typedef __attribute__((ext_vector_type(4))) float f32x4;

__device__ __forceinline__ unsigned short f2bf(float x) {
  union { float f; unsigned u; } c; c.f = x;
  unsigned r = c.u + 0x7FFF + ((c.u >> 16) & 1);
  return (unsigned short)(r >> 16);
}
__device__ __forceinline__ float bf2f(unsigned short u) {
  union { unsigned u; float f; } c; c.u = ((unsigned)u) << 16;
  return c.f;
}

// ---------------------------------------------------------------------------
// Encoder v2: ONE THREAD PER ROW. out = relu(LN(in @ W + b)).
// ---------------------------------------------------------------------------
template <int D>
__global__ __launch_bounds__(256) void encode_row_kernel(
    const float* __restrict__ in,
    const float* __restrict__ W, const float* __restrict__ b,
    const float* __restrict__ g, const float* __restrict__ beta,
    float* __restrict__ out, unsigned short* __restrict__ outb, int R) {
  int row = blockIdx.x * 256 + threadIdx.x;
  if (row >= R) return;
  float vin[D];
#pragma unroll
  for (int k = 0; k < D; k++) vin[k] = in[(size_t)row * D + k];
  float y[96];
  float s = 0.f, s2 = 0.f;
#pragma unroll
  for (int j = 0; j < 96; j++) {
    float v = b[j];
#pragma unroll
    for (int k = 0; k < D; k++) v += vin[k] * W[k * 96 + j];
    y[j] = v;
    s += v;
    s2 += v * v;
  }
  float mu = s * (1.f / 96.f);
  float var = s2 * (1.f / 96.f) - mu * mu;
  float rs = rsqrtf(var + 1e-5f);
#pragma unroll
  for (int c = 0; c < 12; c++) {
    u16x8 pk;
    float yo[8];
#pragma unroll
    for (int j = 0; j < 8; j++) {
      int jj = c * 8 + j;
      float v = (y[jj] - mu) * rs * g[jj] + beta[jj];
      v = fmaxf(v, 0.f);
      yo[j] = v;
      pk[j] = f2bf(v);
    }
    *(u16x8*)&outb[(size_t)row * 96 + c * 8] = pk;
    if (out) {
      f32x4 o0 = {yo[0], yo[1], yo[2], yo[3]};
      f32x4 o1 = {yo[4], yo[5], yo[6], yo[7]};
      *(f32x4*)&out[(size_t)row * 96 + c * 8] = o0;
      *(f32x4*)&out[(size_t)row * 96 + c * 8 + 4] = o1;
    }
  }
}

// ---------------------------------------------------------------------------
// Weight prep
// ---------------------------------------------------------------------------
__global__ void convW_kernel(const float* __restrict__ We,
                             unsigned short* __restrict__ WeTb,
                             const float* __restrict__ Wl,
                             unsigned short* __restrict__ WlTb,
                             const float* __restrict__ Wr,
                             unsigned short* __restrict__ WrTb,
                             const float* __restrict__ p1w,
                             unsigned short* __restrict__ p1wT,
                             const float* __restrict__ p2w,
                             unsigned short* __restrict__ p2wT) {
  int idx = blockIdx.x * 256 + threadIdx.x;
  if (idx < 3 * 576 * 96) {
    int l = idx / (576 * 96);
    int rem = idx % (576 * 96);
    int n = rem / 96, k = rem % 96;
    size_t sidx = (size_t)l * 96 * 576 + (size_t)k * 576 + n;
    WeTb[idx] = f2bf(We[sidx]);
    WlTb[idx] = f2bf(Wl[sidx]);
    WrTb[idx] = f2bf(Wr[sidx]);
  }
  if (idx < 128 * 288) {
    int n = idx / 288, k = idx % 288;
    p1wT[idx] = f2bf(p1w[(size_t)k * 128 + n]);
  }
  if (idx < 64 * 128) {
    int n = idx / 128, k = idx % 128;
    p2wT[idx] = f2bf(p2w[(size_t)k * 64 + n]);
  }
}

// ---------------------------------------------------------------------------
// CSR build by dst
// ---------------------------------------------------------------------------
__global__ void hist_kernel(const int* __restrict__ dst, int* __restrict__ deg) {
  int e = blockIdx.x * blockDim.x + threadIdx.x;
  if (e < NE) atomicAdd(&deg[dst[e]], 1);
}

// fast scan: 20 nodes/thread serial prefix + wave shfl scan + 16-wave scan
__global__ __launch_bounds__(1024) void scan_kernel(
    const int* __restrict__ deg, int* __restrict__ rowptr, int* __restrict__ cursor) {
  __shared__ int wsum[16];
  int t = threadIdx.x;
  int base = t * 20;
  int loc[20];
  int s = 0;
#pragma unroll
  for (int j = 0; j < 20; j++) {
    int idx = base + j;
    int v = (idx < NN) ? deg[idx] : 0;
    loc[j] = s;
    s += v;
  }
  int lane = t & 63, wv = t >> 6;
  int inc = s;
#pragma unroll
  for (int off = 1; off < 64; off <<= 1) {
    int up = __shfl_up(inc, off);
    if (lane >= off) inc += up;
  }
  if (lane == 63) wsum[wv] = inc;
  __syncthreads();
  if (wv == 0) {
    int wval = (lane < 16) ? wsum[lane] : 0;
#pragma unroll
    for (int off = 1; off < 16; off <<= 1) {
      int up = __shfl_up(wval, off);
      if (lane >= off) wval += up;
    }
    if (lane < 16) wsum[lane] = wval;
  }
  __syncthreads();
  int wbase = (wv > 0) ? wsum[wv - 1] : 0;
  int excl = wbase + inc - s;
#pragma unroll
  for (int j = 0; j < 20; j++) {
    int idx = base + j;
    if (idx < NN) { rowptr[idx] = excl + loc[j]; cursor[idx] = excl + loc[j]; }
  }
  if (t == 0) rowptr[NN] = NE;
}

__global__ void scatter_kernel(const int* __restrict__ src,
                               const int* __restrict__ dst,
                               int* __restrict__ cursor, int* __restrict__ eidx,
                               int* __restrict__ srcp, int* __restrict__ dstp) {
  int e = blockIdx.x * blockDim.x + threadIdx.x;
  if (e < NE) {
    int d = dst[e];
    int p = atomicAdd(&cursor[d], 1);
    eidx[p] = e;
    srcp[p] = src[e];
    dstp[p] = d;
  }
}

// ---------------------------------------------------------------------------
// xlxr via MFMA (verified R8)
// ---------------------------------------------------------------------------
__global__ __launch_bounds__(256) void xlxr_mfma_kernel(
    const unsigned short* __restrict__ Xb,    // [NN][96]
    const unsigned short* __restrict__ WlTb,  // [576][96]
    const float* __restrict__ bl,
    const unsigned short* __restrict__ WrTb,  // [576][96]
    const float* __restrict__ br,
    unsigned short* __restrict__ xlb, unsigned short* __restrict__ xrb) {
  int t = threadIdx.x;
  int wave = t >> 6, lane = t & 63;
  int l15 = lane & 15, quad = lane >> 4;
  int node = blockIdx.x * 64 + wave * 16 + l15;
  int nclamp = (node < NN) ? node : (NN - 1);
  bool valid = node < NN;
  const unsigned short* brow = &Xb[(size_t)nclamp * 96 + quad * 8];
  bf16x8 b0 = *(const bf16x8*)&brow[0];
  bf16x8 b1 = *(const bf16x8*)&brow[32];
  bf16x8 b2 = *(const bf16x8*)&brow[64];
#pragma unroll
  for (int mt = 0; mt < 36; mt++) {
    int wc = mt * 16 + l15;
    const unsigned short* aL = &WlTb[(size_t)wc * 96 + quad * 8];
    f32x4 accL = {0.f, 0.f, 0.f, 0.f};
    accL = __builtin_amdgcn_mfma_f32_16x16x32_bf16(*(const bf16x8*)&aL[0], b0, accL, 0, 0, 0);
    accL = __builtin_amdgcn_mfma_f32_16x16x32_bf16(*(const bf16x8*)&aL[32], b1, accL, 0, 0, 0);
    accL = __builtin_amdgcn_mfma_f32_16x16x32_bf16(*(const bf16x8*)&aL[64], b2, accL, 0, 0, 0);
    const unsigned short* aR = &WrTb[(size_t)wc * 96 + quad * 8];
    f32x4 accR = {0.f, 0.f, 0.f, 0.f};
    accR = __builtin_amdgcn_mfma_f32_16x16x32_bf16(*(const bf16x8*)&aR[0], b0, accR, 0, 0, 0);
    accR = __builtin_amdgcn_mfma_f32_16x16x32_bf16(*(const bf16x8*)&aR[32], b1, accR, 0, 0, 0);
    accR = __builtin_amdgcn_mfma_f32_16x16x32_bf16(*(const bf16x8*)&aR[64], b2, accR, 0, 0, 0);
    if (valid) {
      int c0 = mt * 16 + quad * 4;
      float4 bbL = *(const float4*)&bl[c0];
      float4 bbR = *(const float4*)&br[c0];
      ushort4 pL, pR;
      pL.x = f2bf(accL[0] + bbL.x); pL.y = f2bf(accL[1] + bbL.y);
      pL.z = f2bf(accL[2] + bbL.z); pL.w = f2bf(accL[3] + bbL.w);
      pR.x = f2bf(accR[0] + bbR.x); pR.y = f2bf(accR[1] + bbR.y);
      pR.z = f2bf(accR[2] + bbR.z); pR.w = f2bf(accR[3] + bbR.w);
      *(ushort4*)&xlb[(size_t)node * 576 + c0] = pL;
      *(ushort4*)&xrb[(size_t)node * 576 + c0] = pR;
    }
  }
}

// ---------------------------------------------------------------------------
// Logits v7: 64 edges / 256-thread block, nt-split across the 4 waves.
// ---------------------------------------------------------------------------
__global__ __launch_bounds__(256) void logits_mfma_kernel(
    const unsigned short* __restrict__ EMBb,   // [NE][96]
    const unsigned short* __restrict__ WeTb,   // [576][96]
    const float* __restrict__ attw,            // [576]
    const unsigned short* __restrict__ XLb,    // [NN][576]
    const unsigned short* __restrict__ XRb,    // [NN][576]
    const int* __restrict__ eidx, const int* __restrict__ srcp,
    const int* __restrict__ dstp,
    float* __restrict__ logp) {               // [NE][6] permuted order
  __shared__ __align__(16) unsigned short emb[64][104];
  __shared__ __align__(16) unsigned short eeb[64][200];
  __shared__ int sd[64][2];
  int t = threadIdx.x;
  int p0 = blockIdx.x * 64;
  if (t < 128) sd[t >> 1][t & 1] = (t & 1) ? dstp[p0 + (t >> 1)] : srcp[p0 + (t >> 1)];
  {
    // stage emb: thread t loads edge (t>>2), 24 elems at (t&3)*24 (48B)
    int e = t >> 2, c0 = (t & 3) * 24;
    int erow = eidx[p0 + e];
    const unsigned short* sp = &EMBb[(size_t)erow * 96 + c0];
    *(bf16x8*)&emb[e][c0]      = *(const bf16x8*)&sp[0];
    *(bf16x8*)&emb[e][c0 + 8]  = *(const bf16x8*)&sp[8];
    *(bf16x8*)&emb[e][c0 + 16] = *(const bf16x8*)&sp[16];
  }
  __syncthreads();

  int wave = t >> 6, lane = t & 63;
  int l15 = lane & 15, quad = lane >> 4;
  int el = t >> 2;             // edge (0..63) for combine phase
  int cq = (t & 3) * 24;
  int gsrc = sd[el][0];
  int gdst = sd[el][1];

  for (int hp = 0; hp < 3; hp++) {
    int h0 = hp * 2, h1 = hp * 2 + 1;
    // prefetch gathers for this head-pair (overlap with MFMA phase)
    const unsigned short* xl0 = &XLb[(size_t)gsrc * 576 + h0 * 96 + cq];
    const unsigned short* xr0 = &XRb[(size_t)gdst * 576 + h0 * 96 + cq];
    const unsigned short* xl1 = &XLb[(size_t)gsrc * 576 + h1 * 96 + cq];
    const unsigned short* xr1 = &XRb[(size_t)gdst * 576 + h1 * 96 + cq];
    bf16x8 gl0[3], gr0[3], gl1[3], gr1[3];
#pragma unroll
    for (int c8 = 0; c8 < 3; c8++) {
      gl0[c8] = *(const bf16x8*)&xl0[c8 * 8];
      gr0[c8] = *(const bf16x8*)&xr0[c8 * 8];
      gl1[c8] = *(const bf16x8*)&xl1[c8 * 8];
      gr1[c8] = *(const bf16x8*)&xr1[c8 * 8];
    }
    // ee for heads (h0,h1): wave handles 3 col-tiles x 4 edge-tiles
#pragma unroll
    for (int k = 0; k < 3; k++) {
      int ntg = wave * 3 + k;
      int col = hp * 192 + ntg * 16 + l15;
      const unsigned short* brow = &WeTb[(size_t)col * 96 + quad * 8];
      bf16x8 b0 = *(const bf16x8*)&brow[0];
      bf16x8 b1 = *(const bf16x8*)&brow[32];
      bf16x8 b2 = *(const bf16x8*)&brow[64];
#pragma unroll
      for (int et = 0; et < 4; et++) {
        const unsigned short* ar = &emb[et * 16 + l15][quad * 8];
        bf16x8 a0 = *(const bf16x8*)&ar[0];
        bf16x8 a1 = *(const bf16x8*)&ar[32];
        bf16x8 a2 = *(const bf16x8*)&ar[64];
        f32x4 acc = {0.f, 0.f, 0.f, 0.f};
        acc = __builtin_amdgcn_mfma_f32_16x16x32_bf16(a0, b0, acc, 0, 0, 0);
        acc = __builtin_amdgcn_mfma_f32_16x16x32_bf16(a1, b1, acc, 0, 0, 0);
        acc = __builtin_amdgcn_mfma_f32_16x16x32_bf16(a2, b2, acc, 0, 0, 0);
#pragma unroll
        for (int r = 0; r < 4; r++)
          eeb[et * 16 + quad * 4 + r][ntg * 16 + l15] = f2bf(acc[r]);
      }
    }
    __syncthreads();
    // combine: leaky + attw dot for both heads (4 threads/edge, 24 cols each)
    float pl0 = 0.f, pl1 = 0.f;
    {
      const unsigned short* ee0 = &eeb[el][cq];
      const unsigned short* ee1 = &eeb[el][96 + cq];
      const f32x4* ap0 = (const f32x4*)&attw[h0 * 96 + cq];
      const f32x4* ap1 = (const f32x4*)&attw[h1 * 96 + cq];
#pragma unroll
      for (int c8 = 0; c8 < 3; c8++) {
        bf16x8 ev0 = *(const bf16x8*)&ee0[c8 * 8];
        bf16x8 ev1 = *(const bf16x8*)&ee1[c8 * 8];
        f32x4 a00 = ap0[c8 * 2], a01 = ap0[c8 * 2 + 1];
        f32x4 a10 = ap1[c8 * 2], a11 = ap1[c8 * 2 + 1];
#pragma unroll
        for (int j = 0; j < 4; j++) {
          float v0 = bf2f((unsigned short)ev0[j]) +
                     bf2f((unsigned short)gl0[c8][j]) +
                     bf2f((unsigned short)gr0[c8][j]);
          v0 = (v0 > 0.f) ? v0 : 0.2f * v0;
          pl0 += v0 * a00[j];
          float w0 = bf2f((unsigned short)ev0[j + 4]) +
                     bf2f((unsigned short)gl0[c8][j + 4]) +
                     bf2f((unsigned short)gr0[c8][j + 4]);
          w0 = (w0 > 0.f) ? w0 : 0.2f * w0;
          pl0 += w0 * a01[j];
          float v1 = bf2f((unsigned short)ev1[j]) +
                     bf2f((unsigned short)gl1[c8][j]) +
                     bf2f((unsigned short)gr1[c8][j]);
          v1 = (v1 > 0.f) ? v1 : 0.2f * v1;
          pl1 += v1 * a10[j];
          float w1 = bf2f((unsigned short)ev1[j + 4]) +
                     bf2f((unsigned short)gl1[c8][j + 4]) +
                     bf2f((unsigned short)gr1[c8][j + 4]);
          w1 = (w1 > 0.f) ? w1 : 0.2f * w1;
          pl1 += w1 * a11[j];
        }
      }
    }
    pl0 += __shfl_xor(pl0, 1); pl0 += __shfl_xor(pl0, 2);
    pl1 += __shfl_xor(pl1, 1); pl1 += __shfl_xor(pl1, 2);
    if ((t & 3) == 0) {
      size_t base = (size_t)(p0 + el) * 6 + hp * 2;
      logp[base] = pl0;
      logp[base + 1] = pl1;
    }
    __syncthreads();
  }
}

// ---------------------------------------------------------------------------
// Alpha: wave-per-node segment softmax over dst-sorted logits.
// ---------------------------------------------------------------------------
__global__ __launch_bounds__(256) void alpha_kernel(
    const float* __restrict__ logp, const int* __restrict__ rowptr,
    float* __restrict__ alpha) {
  int node = blockIdx.x * 4 + (threadIdx.x >> 6);
  int lane = threadIdx.x & 63;
  if (node >= NN) return;
  int r0 = rowptr[node], r1 = rowptr[node + 1];
  int d = r1 - r0;
  if (d == 0) return;
  if (d <= 64) {
    bool act = lane < d;
    int p = r0 + (act ? lane : (d - 1));
    float lg[6];
#pragma unroll
    for (int h = 0; h < 6; h++) lg[h] = logp[(size_t)p * 6 + h];
#pragma unroll
    for (int h = 0; h < 6; h++) {
      float m = act ? lg[h] : -1e30f;
#pragma unroll
      for (int off = 32; off > 0; off >>= 1) m = fmaxf(m, __shfl_xor(m, off));
      float w = act ? expf(lg[h] - m) : 0.f;
      float s = w;
#pragma unroll
      for (int off = 32; off > 0; off >>= 1) s += __shfl_xor(s, off);
      if (act) alpha[(size_t)p * 6 + h] = w / (s + 1e-16f);
    }
  } else {
    float m[6], s[6];
#pragma unroll
    for (int h = 0; h < 6; h++) { m[h] = -1e30f; s[h] = 0.f; }
    for (int cs = 0; cs < d; cs += 64) {
      int cnt = min(64, d - cs);
      bool act = lane < cnt;
      int p = r0 + cs + (act ? lane : (cnt - 1));
#pragma unroll
      for (int h = 0; h < 6; h++) {
        float lg = act ? logp[(size_t)p * 6 + h] : -1e30f;
        float cm = lg;
#pragma unroll
        for (int off = 32; off > 0; off >>= 1) cm = fmaxf(cm, __shfl_xor(cm, off));
        float newm = fmaxf(m[h], cm);
        float w = act ? expf(lg - newm) : 0.f;
        float ss = w;
#pragma unroll
        for (int off = 32; off > 0; off >>= 1) ss += __shfl_xor(ss, off);
        s[h] = s[h] * expf(m[h] - newm) + ss;
        m[h] = newm;
      }
    }
    float inv[6];
#pragma unroll
    for (int h = 0; h < 6; h++) inv[h] = 1.f / (s[h] + 1e-16f);
    for (int cs = 0; cs < d; cs += 64) {
      int cnt = min(64, d - cs);
      if (lane < cnt) {
        int p = r0 + cs + lane;
#pragma unroll
        for (int h = 0; h < 6; h++)
          alpha[(size_t)p * 6 + h] =
              expf(logp[(size_t)p * 6 + h] - m[h]) * inv[h];
      }
    }
  }
}

// ---------------------------------------------------------------------------
// Aggregate v7: head-mean folded into the gather. 96 threads per node, one
// output channel each; per edge a thread reads 6 head values (stride 96,
// wave-coalesced) and dots with alpha[e][0:6] (broadcast) into ONE acc.
// 6 nodes per 576-thread block (3334 blocks vs 20000), no cross-head scratch
// reduce, 6-12 loads in flight per thread. LN done per-node by waves 0..5.
// ---------------------------------------------------------------------------
__global__ __launch_bounds__(576) void aggregate_kernel(
    float* __restrict__ x, unsigned short* __restrict__ xb,
    const unsigned short* __restrict__ XLb,
    const float* __restrict__ alpha, const int* __restrict__ rowptr,
    const int* __restrict__ srcp,
    const float* __restrict__ cbias, const float* __restrict__ lng,
    const float* __restrict__ lnb, int do_elu) {
  int t = threadIdx.x;
  int nb = t / 96, c = t % 96;
  int n = blockIdx.x * 6 + nb;
  bool vn = (n < NN);
  __shared__ float fin[6][96];
  __shared__ float red[6][2];
  int wave = t >> 6, lane = t & 63;
  int r0 = 0, d = 0;
  if (vn) { r0 = rowptr[n]; d = rowptr[n + 1] - r0; }
  float acc = 0.f;
  int j = 0;
  for (; j + 1 < d; j += 2) {
    int p = r0 + j;
    int s0 = srcp[p], s1 = srcp[p + 1];
    const float* ap0 = &alpha[(size_t)p * 6];
    float2 a00 = *(const float2*)&ap0[0];
    float2 a01 = *(const float2*)&ap0[2];
    float2 a02 = *(const float2*)&ap0[4];
    float2 a10 = *(const float2*)&ap0[6];
    float2 a11 = *(const float2*)&ap0[8];
    float2 a12 = *(const float2*)&ap0[10];
    const unsigned short* xp0 = &XLb[(size_t)s0 * 576 + c];
    const unsigned short* xp1 = &XLb[(size_t)s1 * 576 + c];
    unsigned short v00 = xp0[0],   v01 = xp0[96],  v02 = xp0[192];
    unsigned short v03 = xp0[288], v04 = xp0[384], v05 = xp0[480];
    unsigned short v10 = xp1[0],   v11 = xp1[96],  v12 = xp1[192];
    unsigned short v13 = xp1[288], v14 = xp1[384], v15 = xp1[480];
    acc += a00.x * bf2f(v00) + a00.y * bf2f(v01) + a01.x * bf2f(v02) +
           a01.y * bf2f(v03) + a02.x * bf2f(v04) + a02.y * bf2f(v05);
    acc += a10.x * bf2f(v10) + a10.y * bf2f(v11) + a11.x * bf2f(v12) +
           a11.y * bf2f(v13) + a12.x * bf2f(v14) + a12.y * bf2f(v15);
  }
  if (j < d) {
    int p = r0 + j;
    int s0 = srcp[p];
    const float* ap0 = &alpha[(size_t)p * 6];
    float2 a00 = *(const float2*)&ap0[0];
    float2 a01 = *(const float2*)&ap0[2];
    float2 a02 = *(const float2*)&ap0[4];
    const unsigned short* xp0 = &XLb[(size_t)s0 * 576 + c];
    unsigned short v00 = xp0[0],   v01 = xp0[96],  v02 = xp0[192];
    unsigned short v03 = xp0[288], v04 = xp0[384], v05 = xp0[480];
    acc += a00.x * bf2f(v00) + a00.y * bf2f(v01) + a01.x * bf2f(v02) +
           a01.y * bf2f(v03) + a02.x * bf2f(v04) + a02.y * bf2f(v05);
  }
  float fv = 0.f;
  if (vn) {
    float s = acc * (1.f / 6.f) + cbias[c];
    if (do_elu) s = (s > 0.f) ? s : expm1f(s);
    fv = s;
  }
  fin[nb][c] = fv;
  __syncthreads();
  if (wave < 6) {
    float x0 = fin[wave][lane];
    float x1 = (lane < 32) ? fin[wave][64 + lane] : 0.f;
    float s = x0 + x1;
    float s2 = x0 * x0 + x1 * x1;
#pragma unroll
    for (int off = 32; off > 0; off >>= 1) {
      s += __shfl_xor(s, off);
      s2 += __shfl_xor(s2, off);
    }
    if (lane == 0) {
      float mu = s * (1.f / 96.f);
      float var = s2 * (1.f / 96.f) - mu * mu;
      red[wave][0] = mu;
      red[wave][1] = rsqrtf(var + 1e-5f);
    }
  }
  __syncthreads();
  if (vn) {
    float y = (fv - red[nb][0]) * red[nb][1] * lng[c] + lnb[c];
    float nv = x[(size_t)n * 96 + c] + y;
    x[(size_t)n * 96 + c] = nv;
    xb[(size_t)n * 96 + c] = f2bf(nv);
  }
}

// ---------------------------------------------------------------------------
// Predictor v2: LDS-staged weight panels (fragment-order), 4x L2-traffic cut.
// ---------------------------------------------------------------------------
__global__ __launch_bounds__(256) void pred_mfma_kernel(
    const unsigned short* __restrict__ Xb,     // [NN][96]
    const unsigned short* __restrict__ EMBb,   // [NE][96]
    const int* __restrict__ src, const int* __restrict__ dst,
    const unsigned short* __restrict__ p1wT,   // [128][288]
    const float* __restrict__ p1b, const float* __restrict__ p1g,
    const float* __restrict__ p1be,
    const unsigned short* __restrict__ p2wT,   // [64][128]
    const float* __restrict__ p2b, const float* __restrict__ p2g,
    const float* __restrict__ p2be,
    const float* __restrict__ p3w, const float* __restrict__ p3b,
    float* __restrict__ out) {
  __shared__ __align__(16) unsigned short fragB[4 * 9 * 64 * 8];  // 36,864 B
  __shared__ unsigned short h1s[4][16][136];                      // 17,408 B
  int t = threadIdx.x;
  int wave = t >> 6, lane = t & 63;
  int l15 = lane & 15, quad = lane >> 4;
  int ebase = blockIdx.x * 64 + wave * 16;
  int erow = ebase + l15;
  int sN = src[erow], dN = dst[erow];

  bf16x8 A[9];
  const unsigned short* xs = &Xb[(size_t)sN * 96 + quad * 8];
  const unsigned short* xd = &Xb[(size_t)dN * 96 + quad * 8];
  const unsigned short* em = &EMBb[(size_t)erow * 96 + quad * 8];
#pragma unroll
  for (int c = 0; c < 3; c++) {
    A[c]     = *(const bf16x8*)&xs[c * 32];
    A[c + 3] = *(const bf16x8*)&xd[c * 32];
    A[c + 6] = *(const bf16x8*)&em[c * 32];
  }

  // stage p1wT half-1: wave w stages rows nt=w (cols w*16..w*16+15)
  {
    bf16x8 tmp[9];
#pragma unroll
    for (int c = 0; c < 9; c++)
      tmp[c] = *(const bf16x8*)&p1wT[(size_t)(wave * 16 + l15) * 288 + c * 32 + quad * 8];
#pragma unroll
    for (int c = 0; c < 9; c++)
      *(bf16x8*)&fragB[((wave * 9 + c) * 64 + lane) * 8] = tmp[c];
  }
  __syncthreads();

  f32x4 C1[8];
#pragma unroll
  for (int nt = 0; nt < 4; nt++) {
    f32x4 acc = {0.f, 0.f, 0.f, 0.f};
#pragma unroll
    for (int c = 0; c < 9; c++) {
      bf16x8 B = *(const bf16x8*)&fragB[((nt * 9 + c) * 64 + lane) * 8];
      acc = __builtin_amdgcn_mfma_f32_16x16x32_bf16(A[c], B, acc, 0, 0, 0);
    }
    float bias = p1b[nt * 16 + l15];
    acc[0] += bias; acc[1] += bias; acc[2] += bias; acc[3] += bias;
    C1[nt] = acc;
  }
  __syncthreads();
  // stage p1wT half-2: rows nt=4+w
  {
    bf16x8 tmp[9];
#pragma unroll
    for (int c = 0; c < 9; c++)
      tmp[c] = *(const bf16x8*)&p1wT[(size_t)((4 + wave) * 16 + l15) * 288 + c * 32 + quad * 8];
#pragma unroll
    for (int c = 0; c < 9; c++)
      *(bf16x8*)&fragB[((wave * 9 + c) * 64 + lane) * 8] = tmp[c];
  }
  __syncthreads();
#pragma unroll
  for (int nt = 4; nt < 8; nt++) {
    f32x4 acc = {0.f, 0.f, 0.f, 0.f};
#pragma unroll
    for (int c = 0; c < 9; c++) {
      bf16x8 B = *(const bf16x8*)&fragB[(((nt - 4) * 9 + c) * 64 + lane) * 8];
      acc = __builtin_amdgcn_mfma_f32_16x16x32_bf16(A[c], B, acc, 0, 0, 0);
    }
    float bias = p1b[nt * 16 + l15];
    acc[0] += bias; acc[1] += bias; acc[2] += bias; acc[3] += bias;
    C1[nt] = acc;
  }
  __syncthreads();  // all fragB reads done before layer-2 restage
  // stage p2wT: wave w stages rows nt2=w (overlaps LN math below)
  {
    bf16x8 tmp[4];
#pragma unroll
    for (int c = 0; c < 4; c++)
      tmp[c] = *(const bf16x8*)&p2wT[(size_t)(wave * 16 + l15) * 128 + c * 32 + quad * 8];
#pragma unroll
    for (int c = 0; c < 4; c++)
      *(bf16x8*)&fragB[((wave * 4 + c) * 64 + lane) * 8] = tmp[c];
  }

  float mu1[4], rs1[4];
#pragma unroll
  for (int r = 0; r < 4; r++) {
    float s = 0.f, s2 = 0.f;
#pragma unroll
    for (int nt = 0; nt < 8; nt++) { float v = C1[nt][r]; s += v; s2 += v * v; }
    s += __shfl_xor(s, 1);  s += __shfl_xor(s, 2);
    s += __shfl_xor(s, 4);  s += __shfl_xor(s, 8);
    s2 += __shfl_xor(s2, 1); s2 += __shfl_xor(s2, 2);
    s2 += __shfl_xor(s2, 4); s2 += __shfl_xor(s2, 8);
    float mu = s * (1.f / 128.f);
    float var = s2 * (1.f / 128.f) - mu * mu;
    mu1[r] = mu;
    rs1[r] = rsqrtf(var + 1e-5f);
  }
#pragma unroll
  for (int nt = 0; nt < 8; nt++) {
    float g = p1g[nt * 16 + l15], be = p1be[nt * 16 + l15];
#pragma unroll
    for (int r = 0; r < 4; r++) {
      float v = (C1[nt][r] - mu1[r]) * rs1[r] * g + be;
      v = fmaxf(v, 0.f);
      h1s[wave][quad * 4 + r][nt * 16 + l15] = f2bf(v);
    }
  }
  __syncthreads();  // covers h1s writes AND p2wT staging

  f32x4 C2[4];
#pragma unroll
  for (int nt = 0; nt < 4; nt++) {
    f32x4 acc = {0.f, 0.f, 0.f, 0.f};
#pragma unroll
    for (int c = 0; c < 4; c++) {
      bf16x8 Af = *(const bf16x8*)&h1s[wave][l15][c * 32 + quad * 8];
      bf16x8 B = *(const bf16x8*)&fragB[((nt * 4 + c) * 64 + lane) * 8];
      acc = __builtin_amdgcn_mfma_f32_16x16x32_bf16(Af, B, acc, 0, 0, 0);
    }
    float bias = p2b[nt * 16 + l15];
    acc[0] += bias; acc[1] += bias; acc[2] += bias; acc[3] += bias;
    C2[nt] = acc;
  }

  float mu2[4], rs2[4];
#pragma unroll
  for (int r = 0; r < 4; r++) {
    float s = 0.f, s2 = 0.f;
#pragma unroll
    for (int nt = 0; nt < 4; nt++) { float v = C2[nt][r]; s += v; s2 += v * v; }
    s += __shfl_xor(s, 1);  s += __shfl_xor(s, 2);
    s += __shfl_xor(s, 4);  s += __shfl_xor(s, 8);
    s2 += __shfl_xor(s2, 1); s2 += __shfl_xor(s2, 2);
    s2 += __shfl_xor(s2, 4); s2 += __shfl_xor(s2, 8);
    float mu = s * (1.f / 64.f);
    float var = s2 * (1.f / 64.f) - mu * mu;
    mu2[r] = mu;
    rs2[r] = rsqrtf(var + 1e-5f);
  }

  float partial[4] = {0.f, 0.f, 0.f, 0.f};
#pragma unroll
  for (int nt = 0; nt < 4; nt++) {
    float g = p2g[nt * 16 + l15], be = p2be[nt * 16 + l15];
    float pw = p3w[nt * 16 + l15];
#pragma unroll
    for (int r = 0; r < 4; r++) {
      float v = (C2[nt][r] - mu2[r]) * rs2[r] * g + be;
      v = fmaxf(v, 0.f);
      partial[r] += v * pw;
    }
  }
#pragma unroll
  for (int r = 0; r < 4; r++) {
    float p = partial[r];
    p += __shfl_xor(p, 1);
    p += __shfl_xor(p, 2);
    p += __shfl_xor(p, 4);
    p += __shfl_xor(p, 8);
    partial[r] = p;
  }
  if (l15 == 0) {
    float b3 = p3b[0];
#pragma unroll
    for (int r = 0; r < 4; r++)
      out[ebase + quad * 4 + r] = partial[r] + b3;
  }
}

// ---------------------------------------------------------------------------
static inline size_t alignup(size_t v) { return (v + 255) & ~(size_t)255; }

extern "C" void kernel_launch(void* const* d_in, const int* in_sizes, int n_in,
                              void* d_out, int out_size, void* d_ws, size_t ws_size,
                              hipStream_t stream) {
  const float* x_in      = (const float*)d_in[0];
  const float* edge_attr = (const float*)d_in[1];
  const int*   ei        = (const int*)d_in[2];
  const int* src = ei;
  const int* dst = ei + NE;
  const float* ne_w = (const float*)d_in[3];
  const float* ne_b = (const float*)d_in[4];
  const float* ne_g = (const float*)d_in[5];
  const float* ne_be = (const float*)d_in[6];
  const float* ee_w = (const float*)d_in[7];
  const float* ee_b = (const float*)d_in[8];
  const float* ee_g = (const float*)d_in[9];
  const float* ee_be = (const float*)d_in[10];
  const float* Wl = (const float*)d_in[11];
  const float* bl = (const float*)d_in[12];
  const float* Wr = (const float*)d_in[13];
  const float* br = (const float*)d_in[14];
  const float* We = (const float*)d_in[15];
  const float* attw = (const float*)d_in[16];
  const float* cbias = (const float*)d_in[17];
  const float* lng = (const float*)d_in[18];
  const float* lnb = (const float*)d_in[19];
  const float* p1w = (const float*)d_in[20];
  const float* p1b = (const float*)d_in[21];
  const float* p1g = (const float*)d_in[22];
  const float* p1be = (const float*)d_in[23];
  const float* p2w = (const float*)d_in[24];
  const float* p2b = (const float*)d_in[25];
  const float* p2g = (const float*)d_in[26];
  const float* p2be = (const float*)d_in[27];
  const float* p3w = (const float*)d_in[28];
  const float* p3b = (const float*)d_in[29];
  float* out = (float*)d_out;

  // workspace carve (aligned)
  char* w = (char*)d_ws;
  float* X    = (float*)w; w += alignup((size_t)NN * 96 * 4);
  float* LOG  = (float*)w; w += alignup((size_t)NE * 6 * 4);
  float* ALPHA = (float*)w; w += alignup((size_t)NE * 6 * 4);
  unsigned short* EMBb = (unsigned short*)w; w += alignup((size_t)NE * 96 * 2);
  unsigned short* XLb  = (unsigned short*)w; w += alignup((size_t)NN * 576 * 2);
  unsigned short* XRb  = (unsigned short*)w; w += alignup((size_t)NN * 576 * 2);
  unsigned short* Xb   = (unsigned short*)w; w += alignup((size_t)NN * 96 * 2);
  unsigned short* WeTb = (unsigned short*)w; w += alignup((size_t)3 * 576 * 96 * 2);
  unsigned short* WlTb = (unsigned short*)w; w += alignup((size_t)3 * 576 * 96 * 2);
  unsigned short* WrTb = (unsigned short*)w; w += alignup((size_t)3 * 576 * 96 * 2);
  unsigned short* p1wT = (unsigned short*)w; w += alignup((size_t)128 * 288 * 2);
  unsigned short* p2wT = (unsigned short*)w; w += alignup((size_t)64 * 128 * 2);
  int* deg    = (int*)w; w += alignup((size_t)(NN + 1) * 4);
  int* rowptr = (int*)w; w += alignup((size_t)(NN + 1) * 4);
  int* cursor = (int*)w; w += alignup((size_t)NN * 4);
  int* eidx   = (int*)w; w += alignup((size_t)NE * 4);
  int* srcp   = (int*)w; w += alignup((size_t)NE * 4);
  int* dstp   = (int*)w; w += alignup((size_t)NE * 4);

  // encoders + weight prep
  encode_row_kernel<4><<<(NN + 255) / 256, 256, 0, stream>>>(
      x_in, ne_w, ne_b, ne_g, ne_be, X, Xb, NN);
  encode_row_kernel<3><<<(NE + 255) / 256, 256, 0, stream>>>(
      edge_attr, ee_w, ee_b, ee_g, ee_be, nullptr, EMBb, NE);
  convW_kernel<<<(3 * 576 * 96 + 255) / 256, 256, 0, stream>>>(
      We, WeTb, Wl, WlTb, Wr, WrTb, p1w, p1wT, p2w, p2wT);

  // CSR by dst
  hipMemsetAsync(deg, 0, (size_t)(NN + 1) * 4, stream);
  hist_kernel<<<(NE + 255) / 256, 256, 0, stream>>>(dst, deg);
  scan_kernel<<<1, 1024, 0, stream>>>(deg, rowptr, cursor);
  scatter_kernel<<<(NE + 255) / 256, 256, 0, stream>>>(src, dst, cursor, eidx,
                                                       srcp, dstp);

  // 3 GATv2 layers
  for (int i = 0; i < 3; i++) {
    const unsigned short* WlT_i = WlTb + (size_t)i * 576 * 96;
    const float* bl_i = bl + (size_t)i * 576;
    const unsigned short* WrT_i = WrTb + (size_t)i * 576 * 96;
    const float* br_i = br + (size_t)i * 576;
    const unsigned short* WeT_i = WeTb + (size_t)i * 576 * 96;
    const float* aw_i = attw + (size_t)i * 576;
    const float* cb_i = cbias + (size_t)i * 96;
    const float* lg_i = lng + (size_t)i * 96;
    const float* lb_i = lnb + (size_t)i * 96;
    xlxr_mfma_kernel<<<(NN + 63) / 64, 256, 0, stream>>>(Xb, WlT_i, bl_i,
                                                         WrT_i, br_i, XLb, XRb);
    logits_mfma_kernel<<<NE / 64, 256, 0, stream>>>(EMBb, WeT_i, aw_i, XLb, XRb,
                                                    eidx, srcp, dstp, LOG);
    alpha_kernel<<<(NN + 3) / 4, 256, 0, stream>>>(LOG, rowptr, ALPHA);
    aggregate_kernel<<<(NN + 5) / 6, 576, 0, stream>>>(X, Xb, XLb, ALPHA,
                                                       rowptr, srcp,
                                                       cb_i, lg_i, lb_i,
                                                       (i < 2) ? 1 : 0);
  }

  // predictor (MFMA)
  pred_mfma_kernel<<<NE / 64, 256, 0, stream>>>(Xb, EMBb, src, dst,
                                                p1wT, p1b, p1g, p1be,
                                                p2wT, p2b, p2g, p2be,
                                                p3w, p3b, out);
}